// Round 7
// baseline (802.734 us; speedup 1.0000x reference)
//
#include <hip/hip_runtime.h>
#include <hip/hip_bf16.h>

#define D 128
#define KVS 8
typedef unsigned short u16;
typedef unsigned int u32;
typedef __attribute__((ext_vector_type(8))) short short8;
typedef __attribute__((ext_vector_type(16))) float f32x16;
typedef __attribute__((ext_vector_type(4))) u32 u32x4;

__device__ __forceinline__ u16 f2bf(float f){
  u32 u = __builtin_bit_cast(u32, f);
  u32 r = (u + 0x7FFFu + ((u >> 16) & 1u)) >> 16;
  return (u16)r;
}
__device__ __forceinline__ float bf2f(u16 u){
  union { u32 i; float f; } v; v.i = ((u32)u) << 16; return v.f;
}

// ---------------- CSR build ----------------
__global__ void k_count(const int* __restrict__ ei1, const int* __restrict__ ei2,
                        int E1, int E2, int N1, int* __restrict__ cnt){
  int i = blockIdx.x*blockDim.x + threadIdx.x;
  int Et = E1 + E2;
  for (; i < Et; i += gridDim.x*blockDim.x){
    int dst = (i < E1) ? ei1[E1 + i] : (ei2[E2 + (i - E1)] + N1);
    atomicAdd(&cnt[dst], 1);
  }
}

__global__ void k_scan(const int* __restrict__ cnt, int* __restrict__ ptr,
                       int* __restrict__ cursor, float* __restrict__ degf, int N){
  __shared__ int part[256];
  int t = threadIdx.x;
  int per = (N + 255) >> 8;
  int lo = t*per, hi = min(N, lo+per);
  int s = 0;
  for (int j=lo;j<hi;j++) s += cnt[j];
  part[t] = s; __syncthreads();
  if (t==0){ int acc=0; for (int j=0;j<256;j++){ int v=part[j]; part[j]=acc; acc+=v; } }
  __syncthreads();
  int acc = part[t];
  for (int j=lo;j<hi;j++){ ptr[j]=acc; cursor[j]=acc; degf[j]=(float)cnt[j]; acc += cnt[j]; }
}

__global__ void k_fill(const int* __restrict__ ei1, const int* __restrict__ ei2,
                       int E1, int E2, int N1, int* __restrict__ cursor, int* __restrict__ srclist){
  int i = blockIdx.x*blockDim.x + threadIdx.x;
  int Et = E1 + E2;
  for (; i < Et; i += gridDim.x*blockDim.x){
    int src, dst;
    if (i < E1){ src = ei1[i]; dst = ei1[E1+i]; }
    else { int j = i - E1; src = ei2[j] + N1; dst = ei2[E2+j] + N1; }
    int p = atomicAdd(&cursor[dst], 1);
    srclist[p] = src;
  }
}

// ---------------- weight convert: f32 [128k][128n] -> bf16 transposed [128n][128k] ----------------
// 8 mats: Wp halves (6) + Wa + Wg
__global__ __launch_bounds__(256) void k_wcvt(const float* __restrict__ Wp, const float* __restrict__ Wa,
                                              const float* __restrict__ Wg, u16* __restrict__ wgt){
  __shared__ u16 tile[128][136];
  int m = blockIdx.x;
  const float* src; u16* dst;
  if (m < 6){ int l = m % 3, half = m / 3; src = Wp + (size_t)l*32768 + half*16384; dst = wgt + (size_t)(half*3 + l)*16384; }
  else if (m == 6){ src = Wa; dst = wgt + (size_t)6*16384; }
  else { src = Wg; dst = wgt + (size_t)7*16384; }
  int t = threadIdx.x;
  int n = t & 127, rh = t >> 7;
  for (int r0=0; r0<128; r0+=2){
    int r = r0 + rh;
    tile[n][r] = f2bf(src[r*128 + n]);
  }
  __syncthreads();
  int row = t >> 1, ch = t & 1;
  #pragma unroll
  for (int i=0;i<4;i++){
    int k0 = ch*64 + i*16;
    short8 a = *(const short8*)&tile[row][k0];
    short8 b = *(const short8*)&tile[row][k0+8];
    *(short8*)&dst[row*128 + k0] = a;
    *(short8*)&dst[row*128 + k0 + 8] = b;
  }
}

// ---------------- fused weights: wfu[l]=(Wn_l@Wm2_l)^T, wfu[3+l]=(Wn_l@Wm1_l)^T (bf16) + fused biases
__global__ __launch_bounds__(256) void k_wfuse(const float* __restrict__ Wn, const float* __restrict__ Wm,
                                               const float* __restrict__ bn, const float* __restrict__ bm,
                                               u16* __restrict__ wfu, float* __restrict__ fbias){
  int blk = blockIdx.x;            // 0..5
  int l = blk % 3, which = blk / 3; // which 0: Wm2 (bottom half), 1: Wm1 (top half)
  const float* A  = Wn + (size_t)l*16384;                              // [r in][k mid]
  const float* Bm = Wm + (size_t)l*32768 + (which==0 ? 16384 : 0);     // [k mid][c out]
  u16* dst  = wfu  + (size_t)(which==0 ? l : 3+l)*16384;               // [c][r]
  float* fb = fbias + (size_t)(which==0 ? l : 3+l)*128;
  int t = threadIdx.x;
  int c0 = (t & 31) * 4;
  int r0 = (t >> 5) * 16;
  float acc[16][4];
  #pragma unroll
  for (int i=0;i<16;i++){ acc[i][0]=0.f; acc[i][1]=0.f; acc[i][2]=0.f; acc[i][3]=0.f; }
  for (int k=0;k<128;k++){
    float4 b4 = *(const float4*)&Bm[k*128 + c0];
    #pragma unroll
    for (int i=0;i<16;i++){
      float a = A[(r0+i)*128 + k];
      acc[i][0] += a*b4.x; acc[i][1] += a*b4.y; acc[i][2] += a*b4.z; acc[i][3] += a*b4.w;
    }
  }
  #pragma unroll
  for (int i=0;i<16;i++)
    #pragma unroll
    for (int j=0;j<4;j++)
      dst[(size_t)(c0+j)*128 + (r0+i)] = f2bf(acc[i][j]);
  if (t < 128){
    float s = 0.f;
    for (int k=0;k<128;k++) s += bn[l*128+k]*Bm[k*128+t];
    if (which) s += bm[l*128+t];
    fb[t] = s;
  }
}

// ---------------- init convert: feats -> x (f32), xb [N][128], xbT [128][N] ----------------
__global__ __launch_bounds__(256) void k_cvt0(const float* __restrict__ src1, const float* __restrict__ src2,
                                              int N1, float* __restrict__ x, u16* __restrict__ xb,
                                              u16* __restrict__ xbT, int N){
  __shared__ u16 tile[128][136];
  int nb = blockIdx.x * 128;
  int t = threadIdx.x;
  int n = t >> 1;
  int ch = t & 1;
  int row = nb + n;
  const float* srow = (row < N1) ? &src1[(size_t)row*D] : &src2[(size_t)(row-N1)*D];
  #pragma unroll
  for (int i=0;i<16;i++){
    int dd = ch*64 + i*4;
    float4 v = *(const float4*)&srow[dd];
    *(float4*)&x[(size_t)row*D + dd] = v;
    u16 b0 = f2bf(v.x), b1 = f2bf(v.y), b2 = f2bf(v.z), b3 = f2bf(v.w);
    ushort4 uv; uv.x=b0; uv.y=b1; uv.z=b2; uv.w=b3;
    *(ushort4*)&xb[(size_t)row*D + dd] = uv;
    tile[dd+0][n]=b0; tile[dd+1][n]=b1; tile[dd+2][n]=b2; tile[dd+3][n]=b3;
  }
  __syncthreads();
  int d = t & 127, hf = t >> 7;
  #pragma unroll
  for (int i=0;i<8;i++){
    short8 v = *(const short8*)&tile[d][hf*64 + i*8];
    *(short8*)&xbT[(size_t)d*N + nb + hf*64 + i*8] = v;
  }
}

// ---------------- MFMA GEMM: out = rs.*(A@W1 + bias) + B@W2 + addin [+ column sums] ----------------
__global__ __launch_bounds__(256) void k_gemm(
    const u16* __restrict__ A, const u16* __restrict__ W1T,
    const u16* __restrict__ B, const u16* __restrict__ W2T,
    const float* __restrict__ bias, const float* __restrict__ rs,
    const float* __restrict__ addin,
    float* __restrict__ of, u16* __restrict__ ob, float* __restrict__ csums, int N)
{
  __shared__ __align__(16) u16 Wsw[2][16384];
  const int t = threadIdx.x;
  const int w4 = t >> 6;
  const int lane = t & 63;
  const int l31 = lane & 31;
  const int hi = lane >> 5;
  const int rb = blockIdx.x * 32;

  #pragma unroll
  for (int i=0;i<8;i++){
    int slot = i*256 + t;
    int row = slot >> 4, g = slot & 15;
    short8 v = *(const short8*)(W1T + row*128 + g*8);
    *(short8*)((char*)&Wsw[0][0] + row*256 + ((g ^ (row&7))*16)) = v;
  }
  if (B){
    #pragma unroll
    for (int i=0;i<8;i++){
      int slot = i*256 + t;
      int row = slot >> 4, g = slot & 15;
      short8 v = *(const short8*)(W2T + row*128 + g*8);
      *(short8*)((char*)&Wsw[1][0] + row*256 + ((g ^ (row&7))*16)) = v;
    }
  }
  short8 af[8], bfr[8];
  #pragma unroll
  for (int g=0; g<8; g++)
    af[g] = *(const short8*)(A + (size_t)(rb + l31)*D + (2*g + hi)*8);
  if (B){
    #pragma unroll
    for (int g=0; g<8; g++)
      bfr[g] = *(const short8*)(B + (size_t)(rb + l31)*D + (2*g + hi)*8);
  }
  __syncthreads();

  f32x16 acc1, acc2;
  #pragma unroll
  for (int i=0;i<16;i++){ acc1[i]=0.f; acc2[i]=0.f; }
  const int wrow = w4*32 + l31;   // output column
  #pragma unroll
  for (int s=0;s<8;s++){
    int gr = 2*s + hi;
    short8 wf = *(const short8*)((const char*)&Wsw[0][0] + wrow*256 + ((gr ^ (wrow&7))*16));
    acc1 = __builtin_amdgcn_mfma_f32_32x32x16_bf16(af[s], wf, acc1, 0,0,0);
  }
  if (B){
    #pragma unroll
    for (int s=0;s<8;s++){
      int gr = 2*s + hi;
      short8 wf = *(const short8*)((const char*)&Wsw[1][0] + wrow*256 + ((gr ^ (wrow&7))*16));
      acc2 = __builtin_amdgcn_mfma_f32_32x32x16_bf16(bfr[s], wf, acc2, 0,0,0);
    }
  }
  const int col = wrow;
  float bv = bias ? bias[col] : 0.0f;
  float ssum = 0.f, sq = 0.f;
  #pragma unroll
  for (int r=0;r<16;r++){
    int rr = (r&3) + 8*(r>>2) + 4*hi;
    size_t grow = (size_t)(rb + rr);
    float v = acc1[r] + bv;
    if (rs) v *= rs[grow];
    if (B) v += acc2[r];
    if (addin) v += addin[grow*D + col];
    if (of) of[grow*D + col] = v;
    if (ob) ob[grow*D + col] = f2bf(v);
    ssum += v; sq += v*v;
  }
  if (csums){
    atomicAdd(&csums[col], ssum);
    atomicAdd(&csums[128+col], sq);
  }
}

// S[v] = sum over in-edges of hb[src] (bf16 in, f32 out)
__global__ __launch_bounds__(256) void k_gather(const u16* __restrict__ hb, const int* __restrict__ ptr,
                          const int* __restrict__ cnt, const int* __restrict__ srclist,
                          float* __restrict__ Sg, int N){
  int f = threadIdx.x & 127, sub = threadIdx.x >> 7;
  int v = blockIdx.x*2 + sub;
  if (v >= N) return;
  int b = ptr[v], n = cnt[v];
  float a0=0.f, a1=0.f, a2=0.f, a3=0.f;
  int j=0;
  for (; j+3<n; j+=4){
    int s0=srclist[b+j], s1=srclist[b+j+1], s2=srclist[b+j+2], s3=srclist[b+j+3];
    a0 += bf2f(hb[(size_t)s0*D + f]);
    a1 += bf2f(hb[(size_t)s1*D + f]);
    a2 += bf2f(hb[(size_t)s2*D + f]);
    a3 += bf2f(hb[(size_t)s3*D + f]);
  }
  for (; j<n; j++) a0 += bf2f(hb[(size_t)srclist[b+j]*D + f]);
  Sg[(size_t)v*D + f] = (a0+a1)+(a2+a3);
}

// ---------------- MFMA flash cross-attention (bf16 partials, exp2 softmax, setprio) ----------------
__global__ __launch_bounds__(256, 2) void k_flash_mfma(
    const u16* __restrict__ xb, const u16* __restrict__ xbT,
    int N1, int N2, int Ntot,
    u16* __restrict__ Opartb, float* __restrict__ MLpart)
{
  __shared__ __align__(16) u16 Kbuf[2][4096];   // [32 key][128 d], granule^=(row&7)
  __shared__ __align__(16) u16 Vbuf[2][4096];   // [128 d][32 key], granule^=(d&3)

  const float L2E = 1.44269504f;
  const int t = threadIdx.x;
  const int w = t >> 6;
  const int lane = t & 63;
  const int l31 = lane & 31;
  const int hi = lane >> 5;

  const int qb = blockIdx.x / KVS;
  const int sp = blockIdx.x % KVS;
  const int qbase = qb * 128;
  const int qs = qbase + w*32;
  const bool isY = qbase >= N1;
  const int kv0 = isY ? 0 : N1;
  const int kvlen = isY ? N1 : N2;
  const int Lk = kvlen / KVS;
  const int kstart = kv0 + sp*Lk;
  const int ntiles = Lk >> 5;

  short8 qf[8];
  #pragma unroll
  for (int c = 0; c < 8; ++c)
    qf[c] = *(const short8*)(xb + (size_t)(qs + l31)*D + c*16 + hi*8);

  const int kr = t >> 3;
  const int kg = (t & 7) * 2;
  const int vd = t >> 1;
  const int vj = (t & 1) * 2;
  const int kw0 = kr*256 + ((kg     ^ (kr & 7))*16);
  const int kw1 = kr*256 + (((kg+1) ^ (kr & 7))*16);
  const int vw0 = vd*64  + (((vj     ^ vd) & 3)*16);
  const int vw1 = vd*64  + ((((vj+1) ^ vd) & 3)*16);

  f32x16 O[4];
  #pragma unroll
  for (int mt=0; mt<4; ++mt)
    #pragma unroll
    for (int i=0;i<16;i++) O[mt][i] = 0.f;
  float m_run = -3.0e38f, l_run = 0.0f;   // m_run in base-2 domain

  {
    int kb = kstart;
    short8 a0 = *(const short8*)(xb  + (size_t)(kb+kr)*D + kg*8);
    short8 a1 = *(const short8*)(xb  + (size_t)(kb+kr)*D + (kg+1)*8);
    short8 v0 = *(const short8*)(xbT + (size_t)vd*Ntot + kb + vj*8);
    short8 v1 = *(const short8*)(xbT + (size_t)vd*Ntot + kb + (vj+1)*8);
    *(short8*)((char*)&Kbuf[0][0] + kw0) = a0;
    *(short8*)((char*)&Kbuf[0][0] + kw1) = a1;
    *(short8*)((char*)&Vbuf[0][0] + vw0) = v0;
    *(short8*)((char*)&Vbuf[0][0] + vw1) = v1;
  }
  __syncthreads();

  for (int tt = 0; tt < ntiles; ++tt){
    const int cur = tt & 1;
    const int nxt = cur ^ 1;
    short8 a0, a1, v0, v1;
    const bool more = (tt+1 < ntiles);
    if (more){
      int kb = kstart + (tt+1)*32;
      a0 = *(const short8*)(xb  + (size_t)(kb+kr)*D + kg*8);
      a1 = *(const short8*)(xb  + (size_t)(kb+kr)*D + (kg+1)*8);
      v0 = *(const short8*)(xbT + (size_t)vd*Ntot + kb + vj*8);
      v1 = *(const short8*)(xbT + (size_t)vd*Ntot + kb + (vj+1)*8);
    }

    const char* Klds = (const char*)&Kbuf[cur][0];
    const char* Vlds = (const char*)&Vbuf[cur][0];

    // ---- S^T = K @ Q^T
    f32x16 sa, sb;
    #pragma unroll
    for (int i=0;i<16;i++){ sa[i]=0.f; sb[i]=0.f; }
    __builtin_amdgcn_s_setprio(1);
    #pragma unroll
    for (int c = 0; c < 8; c += 2){
      int gr0 = 2*c + hi;
      short8 ka = *(const short8*)(Klds + l31*256 + ((gr0 ^ (l31&7))*16));
      sa = __builtin_amdgcn_mfma_f32_32x32x16_bf16(ka, qf[c], sa, 0,0,0);
      int gr1 = 2*(c+1) + hi;
      short8 kbf = *(const short8*)(Klds + l31*256 + ((gr1 ^ (l31&7))*16));
      sb = __builtin_amdgcn_mfma_f32_32x32x16_bf16(kbf, qf[c+1], sb, 0,0,0);
    }
    __builtin_amdgcn_s_setprio(0);
    f32x16 s;
    #pragma unroll
    for (int i=0;i<16;i++) s[i] = sa[i] + sb[i];

    // ---- online softmax, base-2 domain, defer-max
    float tm = s[0];
    #pragma unroll
    for (int i=1;i<16;i++) tm = fmaxf(tm, s[i]);
    tm = fmaxf(tm, __shfl_xor(tm, 32, 64));
    float tm2 = tm * L2E;
    if (__any(tm2 > m_run + 11.544f)){
      float mnew = fmaxf(m_run, tm2);
      float alpha = exp2f(m_run - mnew);
      l_run *= alpha;
      m_run = mnew;
      #pragma unroll
      for (int i=0;i<16;i++){ O[0][i]*=alpha; O[1][i]*=alpha; O[2][i]*=alpha; O[3][i]*=alpha; }
    }
    float rsum = 0.f;
    #pragma unroll
    for (int i=0;i<16;i++){ float p = exp2f(fmaf(s[i], L2E, -m_run)); s[i]=p; rsum += p; }
    rsum += __shfl_xor(rsum, 32, 64);
    l_run += rsum;

    // ---- pack P to bf16 pairs
    u32 pk[8];
    #pragma unroll
    for (int i=0;i<8;i++){
      u32 r;
      asm("v_cvt_pk_bf16_f32 %0, %1, %2" : "=v"(r) : "v"(s[2*i]), "v"(s[2*i+1]));
      pk[i] = r;
    }

    // ---- PV: O^T += V^T @ P^T
    #pragma unroll
    for (int ks=0; ks<2; ++ks){
      u32 send0 = hi ? pk[(2*ks)*2+0] : pk[(2*ks+1)*2+0];
      u32 send1 = hi ? pk[(2*ks)*2+1] : pk[(2*ks+1)*2+1];
      u32 xv0 = (u32)__shfl_xor((int)send0, 32, 64);
      u32 xv1 = (u32)__shfl_xor((int)send1, 32, 64);
      u32 own0 = hi ? pk[(2*ks+1)*2+0] : pk[(2*ks)*2+0];
      u32 own1 = hi ? pk[(2*ks+1)*2+1] : pk[(2*ks)*2+1];
      u32x4 bv;
      bv.x = hi ? xv0 : own0;
      bv.y = hi ? xv1 : own1;
      bv.z = hi ? own0 : xv0;
      bv.w = hi ? own1 : xv1;
      short8 pf = __builtin_bit_cast(short8, bv);
      __builtin_amdgcn_s_setprio(1);
      #pragma unroll
      for (int mt=0; mt<4; ++mt){
        int dd = mt*32 + l31;
        int j = 2*ks + hi;
        short8 vf = *(const short8*)(Vlds + dd*64 + (((j ^ dd) & 3)*16));
        O[mt] = __builtin_amdgcn_mfma_f32_32x32x16_bf16(vf, pf, O[mt], 0,0,0);
      }
      __builtin_amdgcn_s_setprio(0);
    }

    if (more){
      *(short8*)((char*)&Kbuf[nxt][0] + kw0) = a0;
      *(short8*)((char*)&Kbuf[nxt][0] + kw1) = a1;
      *(short8*)((char*)&Vbuf[nxt][0] + vw0) = v0;
      *(short8*)((char*)&Vbuf[nxt][0] + vw1) = v1;
    }
    __syncthreads();
  }

  const int strip = qs >> 5;
  u16* Od = Opartb + ((size_t)strip*KVS + sp)*4096;
  #pragma unroll
  for (int mt=0; mt<4; ++mt){
    #pragma unroll
    for (int r=0;r<16;r++){
      int dd = mt*32 + (r&3) + 8*(r>>2) + 4*hi;
      Od[dd*32 + l31] = f2bf(O[mt][r]);
    }
  }
  if (lane < 32){
    float* mlp = MLpart + ((size_t)strip*KVS + sp)*64;
    mlp[l31*2+0] = m_run;
    mlp[l31*2+1] = l_run;
  }
}

// ---------------- flash partial combine: attinb = bf16(x - (sum_s w_s O_s)/L) ----------------
__global__ __launch_bounds__(256) void k_fcomb(
    const u16* __restrict__ Opartb, const float* __restrict__ MLpart,
    const float* __restrict__ x, u16* __restrict__ attinb)
{
  __shared__ float cw[KVS][32];
  __shared__ float Tld[128][33];
  const int strip = blockIdx.x;
  const int t = threadIdx.x;
  if (t < 32){
    int q = t;
    const float* mlp = MLpart + (size_t)strip*KVS*64;
    float mv[KVS], lv[KVS];
    float M = -3.0e38f;
    #pragma unroll
    for (int s2=0;s2<KVS;s2++){ mv[s2]=mlp[s2*64+q*2]; lv[s2]=mlp[s2*64+q*2+1]; M = fmaxf(M, mv[s2]); }
    float L = 0.f;
    #pragma unroll
    for (int s2=0;s2<KVS;s2++){ float wv=exp2f(mv[s2]-M); cw[s2][q]=wv; L += wv*lv[s2]; }
    float inv = 1.0f / L;
    #pragma unroll
    for (int s2=0;s2<KVS;s2++) cw[s2][q] *= inv;
  }
  __syncthreads();
  {
    const int d = t >> 1, q0 = (t & 1) * 16;
    const u16* Ob = Opartb + (size_t)strip*KVS*4096;
    float acc[16];
    #pragma unroll
    for (int j=0;j<16;j++) acc[j]=0.f;
    #pragma unroll
    for (int s2=0; s2<KVS; ++s2){
      const u16* row = Ob + s2*4096 + d*32 + q0;
      short8 v8a = *(const short8*)row;
      short8 v8b = *(const short8*)(row + 8);
      #pragma unroll
      for (int j=0;j<8;j++){
        acc[j]   += cw[s2][q0+j]  *bf2f((u16)v8a[j]);
        acc[8+j] += cw[s2][q0+8+j]*bf2f((u16)v8b[j]);
      }
    }
    #pragma unroll
    for (int j=0;j<16;j++) Tld[d][q0+j] = acc[j];
  }
  __syncthreads();
  {
    const int q = t >> 3, c0 = (t & 7) * 16;
    const size_t row = (size_t)(strip*32 + q)*D;
    #pragma unroll
    for (int i=0;i<16;i+=4){
      float4 xr = *(const float4*)&x[row + c0 + i];
      ushort4 o;
      o.x = f2bf(xr.x - Tld[c0+i+0][q]);
      o.y = f2bf(xr.y - Tld[c0+i+1][q]);
      o.z = f2bf(xr.z - Tld[c0+i+2][q]);
      o.w = f2bf(xr.w - Tld[c0+i+3][q]);
      *(ushort4*)&attinb[row + c0 + i] = o;
    }
  }
}

// ---------------- norm + f32/bf16/bf16T write fused ----------------
__global__ __launch_bounds__(256) void k_normcvt(const float* __restrict__ outb,
                        const float* __restrict__ sums,
                        const float* __restrict__ gamma, const float* __restrict__ beta,
                        int N, float* __restrict__ x, u16* __restrict__ xb, u16* __restrict__ xbT){
  __shared__ u16 tile[128][136];
  __shared__ float smu[128], srs[128], sg2[128], sb2[128];
  int t = threadIdx.x;
  if (t < 128){
    float mu = sums[t] / (float)N;
    float var = fmaxf(sums[128+t]/(float)N - mu*mu, 0.0f);
    smu[t]=mu; srs[t]=rsqrtf(var + 1e-5f);
    sg2[t]=gamma[t]; sb2[t]=beta[t];
  }
  __syncthreads();
  int nb = blockIdx.x * 128;
  int n = t >> 1, ch = t & 1;
  #pragma unroll
  for (int i=0;i<16;i++){
    int dd = ch*64 + i*4;
    float4 v = *(const float4*)&outb[(size_t)(nb+n)*D + dd];
    float4 y;
    y.x = (v.x - smu[dd+0])*srs[dd+0]*sg2[dd+0] + sb2[dd+0];
    y.y = (v.y - smu[dd+1])*srs[dd+1]*sg2[dd+1] + sb2[dd+1];
    y.z = (v.z - smu[dd+2])*srs[dd+2]*sg2[dd+2] + sb2[dd+2];
    y.w = (v.w - smu[dd+3])*srs[dd+3]*sg2[dd+3] + sb2[dd+3];
    *(float4*)&x[(size_t)(nb+n)*D + dd] = y;
    u16 b0=f2bf(y.x), b1=f2bf(y.y), b2=f2bf(y.z), b3=f2bf(y.w);
    ushort4 uv; uv.x=b0; uv.y=b1; uv.z=b2; uv.w=b3;
    *(ushort4*)&xb[(size_t)(nb+n)*D + dd] = uv;
    tile[dd+0][n]=b0; tile[dd+1][n]=b1; tile[dd+2][n]=b2; tile[dd+3][n]=b3;
  }
  __syncthreads();
  int d = t & 127, hf = t >> 7;
  #pragma unroll
  for (int i=0;i<8;i++){
    short8 v = *(const short8*)&tile[d][hf*64 + i*8];
    *(short8*)&xbT[(size_t)d*N + nb + hf*64 + i*8] = v;
  }
}

// ---------------- gated readout ----------------
__global__ __launch_bounds__(256) void k_gatepool(
    const float* __restrict__ states, const float* __restrict__ glog,
    int N1, int N, float* __restrict__ gsums)
{
  __shared__ float part[256];
  part[threadIdx.x] = 0.f;
  __syncthreads();
  int wid = threadIdx.x >> 6, lane = threadIdx.x & 63;
  for (int v = blockIdx.x*4 + wid; v < N; v += gridDim.x*4){
    float a0 = glog[(size_t)v*D + lane], a1 = glog[(size_t)v*D + lane + 64];
    float mx = fmaxf(a0,a1);
    #pragma unroll
    for (int off=32; off; off>>=1) mx = fmaxf(mx, __shfl_xor(mx, off, 64));
    float e0 = __expf(a0-mx), e1 = __expf(a1-mx);
    float ss = e0+e1;
    #pragma unroll
    for (int off=32; off; off>>=1) ss += __shfl_xor(ss, off, 64);
    float inv = 1.f/ss;
    int g = (v < N1) ? 0 : 1;
    atomicAdd(&part[g*128 + lane], states[(size_t)v*D+lane]*e0*inv);
    atomicAdd(&part[g*128 + lane + 64], states[(size_t)v*D+lane+64]*e1*inv);
  }
  __syncthreads();
  atomicAdd(&gsums[threadIdx.x], part[threadIdx.x]);
}

__global__ __launch_bounds__(256) void k_emb(
    const float* __restrict__ gsums, const float* __restrict__ Wf,
    const float* __restrict__ bf_, int N1, int N2, float* __restrict__ outp)
{
  __shared__ float mean[256];
  int t = threadIdx.x;
  mean[t] = gsums[t] / ((t < 128) ? (float)N1 : (float)N2);
  __syncthreads();
  int g = t >> 7, dc = t & 127;
  float acc = bf_[dc];
  for (int k=0;k<D;k++) acc += mean[g*128 + k] * Wf[k*D + dc];
  outp[t] = acc;
}

extern "C" void kernel_launch(void* const* d_in, const int* in_sizes, int n_in,
                              void* d_out, int out_size, void* d_ws, size_t ws_size,
                              hipStream_t stream) {
  const float* feats1 = (const float*)d_in[0];
  const int*   ei1    = (const int*)d_in[1];
  const float* feats2 = (const float*)d_in[2];
  const int*   ei2    = (const int*)d_in[3];
  const float* Wn = (const float*)d_in[6];
  const float* bn = (const float*)d_in[7];
  const float* Wm = (const float*)d_in[8];
  const float* bm = (const float*)d_in[9];
  const float* Wp = (const float*)d_in[10];
  const float* bp = (const float*)d_in[11];
  const float* gamma = (const float*)d_in[12];
  const float* beta  = (const float*)d_in[13];
  const float* Wa = (const float*)d_in[14];
  const float* ba = (const float*)d_in[15];
  const float* Wg = (const float*)d_in[16];
  const float* bg = (const float*)d_in[17];
  const float* Wf = (const float*)d_in[18];
  const float* bff = (const float*)d_in[19];

  int N1 = in_sizes[0]/D, E1 = in_sizes[1]/2;
  int N2 = in_sizes[2]/D, E2 = in_sizes[3]/2;
  int N = N1+N2;
  int nstrips = N/32;

  char* w = (char*)d_ws;
  float* x    = (float*)w; w += (size_t)N*D*4;
  u16* xb     = (u16*)w;   w += (size_t)N*D*2;
  u16* xbT    = (u16*)w;   w += (size_t)N*D*2;
  u16* hm2b   = (u16*)w;   w += (size_t)N*D*2;
  u16* aggrb  = (u16*)w;   w += (size_t)N*D*2;
  u16* attinb = (u16*)w;   w += (size_t)N*D*2;
  int* cnt    = (int*)w;   w += (size_t)N*4;
  int* ptr    = (int*)w;   w += (size_t)N*4;
  int* cursor = (int*)w;   w += (size_t)N*4;
  float* degf = (float*)w; w += (size_t)N*4;
  int* srclist= (int*)w;   w += (size_t)(E1+E2)*4;
  float* sums = (float*)w; w += 1024;
  float* gsums= (float*)w; w += 1024;
  u16* wgt    = (u16*)w;   w += (size_t)8*16384*2;
  u16* wfu    = (u16*)w;   w += (size_t)6*16384*2;
  float* fbias= (float*)w; w += (size_t)6*128*4;
  u16* Opartb = (u16*)w;   w += (size_t)nstrips*KVS*4096*2;
  float* MLpart=(float*)w; w += (size_t)nstrips*KVS*64*4;
  // lifetime-disjoint f32 aliases inside Opartb (each consumed before Opartb is rewritten):
  float* Sg     = (float*)Opartb;
  float* outb   = (float*)Opartb + (size_t)N*D;
  float* states = Sg;
  float* glog   = outb;

  hipMemsetAsync(cnt, 0, (size_t)N*4, stream);
  k_count<<<1024,256,0,stream>>>(ei1, ei2, E1, E2, N1, cnt);
  k_scan<<<1,256,0,stream>>>(cnt, ptr, cursor, degf, N);
  k_fill<<<1024,256,0,stream>>>(ei1, ei2, E1, E2, N1, cursor, srclist);
  k_wcvt<<<8,256,0,stream>>>(Wp, Wa, Wg, wgt);
  k_wfuse<<<6,256,0,stream>>>(Wn, Wm, bn, bm, wfu, fbias);
  k_cvt0<<<N/128,256,0,stream>>>(feats1, feats2, N1, x, xb, xbT, N);

  for (int l=0;l<3;l++){
    const u16* fuse2T_l = wfu + (size_t)l*16384;
    const u16* fuse1T_l = wfu + (size_t)(3+l)*16384;
    const float* fb2_l  = fbias + (size_t)l*128;
    const float* fb1_l  = fbias + (size_t)(3+l)*128;
    const u16* Wp1T_l = wgt + (size_t)(0+l)*16384;
    const u16* Wp2T_l = wgt + (size_t)(3+l)*16384;
    const float* bp_l = bp + (size_t)l*D;

    k_flash_mfma<<<(N/128)*KVS,256,0,stream>>>(xb, xbT, N1, N2, N, Opartb, MLpart);
    k_fcomb<<<nstrips,256,0,stream>>>(Opartb, MLpart, x, attinb);
    // hm2 = x@(Wn@Wm2) + bn@Wm2  (bf16 out) — h never materialized
    k_gemm<<<N/32,256,0,stream>>>(xb, fuse2T_l, nullptr, nullptr, fb2_l, nullptr, nullptr, nullptr, hm2b, nullptr, N);
    k_gather<<<N/2,256,0,stream>>>(hm2b, ptr, cnt, srclist, Sg, N);
    // aggr = deg.*(x@(Wn@Wm1) + bn@Wm1 + bm) + Sg
    k_gemm<<<N/32,256,0,stream>>>(xb, fuse1T_l, nullptr, nullptr, fb1_l, degf, Sg, nullptr, aggrb, nullptr, N);
    hipMemsetAsync(sums, 0, 1024, stream);
    // outb = aggr@Wp_top + attin@Wp_bot + bp (f32 out, fused column sums)
    k_gemm<<<N/32,256,0,stream>>>(aggrb, Wp1T_l, attinb, Wp2T_l, bp_l, nullptr, nullptr, outb, nullptr, sums, N);
    k_normcvt<<<N/128,256,0,stream>>>(outb, sums, gamma + (size_t)l*D, beta + (size_t)l*D, N, x, xb, xbT);
  }

  k_gemm<<<N/32,256,0,stream>>>(xb, wgt + (size_t)6*16384, nullptr, nullptr, ba, nullptr, nullptr, states, nullptr, nullptr, N);
  k_gemm<<<N/32,256,0,stream>>>(xb, wgt + (size_t)7*16384, nullptr, nullptr, bg, nullptr, nullptr, glog, nullptr, nullptr, N);
  hipMemsetAsync(gsums, 0, 1024, stream);
  k_gatepool<<<64,256,0,stream>>>(states, glog, N1, N, gsums);
  k_emb<<<1,256,0,stream>>>(gsums, Wf, bff, N1, N2, (float*)d_out);
}

// Round 11
// 656.961 us; speedup vs baseline: 1.2219x; 1.2219x over previous
//
#include <hip/hip_runtime.h>
#include <hip/hip_bf16.h>

#define D 128
#define KVS 8
typedef unsigned short u16;
typedef unsigned int u32;
typedef __attribute__((ext_vector_type(8))) short short8;
typedef __attribute__((ext_vector_type(16))) float f32x16;
typedef __attribute__((ext_vector_type(4))) u32 u32x4;

__device__ __forceinline__ u16 f2bf(float f){
  u32 u = __builtin_bit_cast(u32, f);
  u32 r = (u + 0x7FFFu + ((u >> 16) & 1u)) >> 16;
  return (u16)r;
}
__device__ __forceinline__ float bf2f(u16 u){
  union { u32 i; float f; } v; v.i = ((u32)u) << 16; return v.f;
}

// ---------------- CSR build ----------------
__global__ void k_count(const int* __restrict__ ei1, const int* __restrict__ ei2,
                        int E1, int E2, int N1, int* __restrict__ cnt){
  int i = blockIdx.x*blockDim.x + threadIdx.x;
  int Et = E1 + E2;
  for (; i < Et; i += gridDim.x*blockDim.x){
    int dst = (i < E1) ? ei1[E1 + i] : (ei2[E2 + (i - E1)] + N1);
    atomicAdd(&cnt[dst], 1);
  }
}

__global__ void k_scan(const int* __restrict__ cnt, int* __restrict__ ptr,
                       int* __restrict__ cursor, float* __restrict__ degf, int N){
  __shared__ int part[256];
  int t = threadIdx.x;
  int per = (N + 255) >> 8;
  int lo = t*per, hi = min(N, lo+per);
  int s = 0;
  for (int j=lo;j<hi;j++) s += cnt[j];
  part[t] = s; __syncthreads();
  if (t==0){ int acc=0; for (int j=0;j<256;j++){ int v=part[j]; part[j]=acc; acc+=v; } }
  __syncthreads();
  int acc = part[t];
  for (int j=lo;j<hi;j++){ ptr[j]=acc; cursor[j]=acc; degf[j]=(float)cnt[j]; acc += cnt[j]; }
}

__global__ void k_fill(const int* __restrict__ ei1, const int* __restrict__ ei2,
                       int E1, int E2, int N1, int* __restrict__ cursor, int* __restrict__ srclist){
  int i = blockIdx.x*blockDim.x + threadIdx.x;
  int Et = E1 + E2;
  for (; i < Et; i += gridDim.x*blockDim.x){
    int src, dst;
    if (i < E1){ src = ei1[i]; dst = ei1[E1+i]; }
    else { int j = i - E1; src = ei2[j] + N1; dst = ei2[E2+j] + N1; }
    int p = atomicAdd(&cursor[dst], 1);
    srclist[p] = src;
  }
}

// ---------------- weight convert: f32 [128k][128n] -> bf16 transposed [128n][128k] ----------------
__global__ __launch_bounds__(256) void k_wcvt(const float* __restrict__ Wp, const float* __restrict__ Wa,
                                              const float* __restrict__ Wg, u16* __restrict__ wgt){
  __shared__ u16 tile[128][136];
  int m = blockIdx.x;
  const float* src; u16* dst;
  if (m < 6){ int l = m % 3, half = m / 3; src = Wp + (size_t)l*32768 + half*16384; dst = wgt + (size_t)(half*3 + l)*16384; }
  else if (m == 6){ src = Wa; dst = wgt + (size_t)6*16384; }
  else { src = Wg; dst = wgt + (size_t)7*16384; }
  int t = threadIdx.x;
  int n = t & 127, rh = t >> 7;
  for (int r0=0; r0<128; r0+=2){
    int r = r0 + rh;
    tile[n][r] = f2bf(src[r*128 + n]);
  }
  __syncthreads();
  int row = t >> 1, ch = t & 1;
  #pragma unroll
  for (int i=0;i<4;i++){
    int k0 = ch*64 + i*16;
    short8 a = *(const short8*)&tile[row][k0];
    short8 b = *(const short8*)&tile[row][k0+8];
    *(short8*)&dst[row*128 + k0] = a;
    *(short8*)&dst[row*128 + k0 + 8] = b;
  }
}

// ---------------- fused weights: wfu[l]=(Wn_l@Wm2_l)^T, wfu[3+l]=(Wn_l@Wm1_l)^T (bf16) + fused biases
__global__ __launch_bounds__(256) void k_wfuse(const float* __restrict__ Wn, const float* __restrict__ Wm,
                                               const float* __restrict__ bn, const float* __restrict__ bm,
                                               u16* __restrict__ wfu, float* __restrict__ fbias){
  int blk = blockIdx.x;            // 0..5
  int l = blk % 3, which = blk / 3; // which 0: Wm2 (bottom half), 1: Wm1 (top half)
  const float* A  = Wn + (size_t)l*16384;
  const float* Bm = Wm + (size_t)l*32768 + (which==0 ? 16384 : 0);
  u16* dst  = wfu  + (size_t)(which==0 ? l : 3+l)*16384;
  float* fb = fbias + (size_t)(which==0 ? l : 3+l)*128;
  int t = threadIdx.x;
  int c0 = (t & 31) * 4;
  int r0 = (t >> 5) * 16;
  float acc[16][4];
  #pragma unroll
  for (int i=0;i<16;i++){ acc[i][0]=0.f; acc[i][1]=0.f; acc[i][2]=0.f; acc[i][3]=0.f; }
  for (int k=0;k<128;k++){
    float4 b4 = *(const float4*)&Bm[k*128 + c0];
    #pragma unroll
    for (int i=0;i<16;i++){
      float a = A[(r0+i)*128 + k];
      acc[i][0] += a*b4.x; acc[i][1] += a*b4.y; acc[i][2] += a*b4.z; acc[i][3] += a*b4.w;
    }
  }
  #pragma unroll
  for (int i=0;i<16;i++)
    #pragma unroll
    for (int j=0;j<4;j++)
      dst[(size_t)(c0+j)*128 + (r0+i)] = f2bf(acc[i][j]);
  if (t < 128){
    float s = 0.f;
    for (int k=0;k<128;k++) s += bn[l*128+k]*Bm[k*128+t];
    if (which) s += bm[l*128+t];
    fb[t] = s;
  }
}

// ---------------- init convert: feats -> x (f32), xb [N][128], xbT [128][N] ----------------
__global__ __launch_bounds__(256) void k_cvt0(const float* __restrict__ src1, const float* __restrict__ src2,
                                              int N1, float* __restrict__ x, u16* __restrict__ xb,
                                              u16* __restrict__ xbT, int N){
  __shared__ u16 tile[128][136];
  int nb = blockIdx.x * 128;
  int t = threadIdx.x;
  int n = t >> 1;
  int ch = t & 1;
  int row = nb + n;
  const float* srow = (row < N1) ? &src1[(size_t)row*D] : &src2[(size_t)(row-N1)*D];
  #pragma unroll
  for (int i=0;i<16;i++){
    int dd = ch*64 + i*4;
    float4 v = *(const float4*)&srow[dd];
    *(float4*)&x[(size_t)row*D + dd] = v;
    u16 b0 = f2bf(v.x), b1 = f2bf(v.y), b2 = f2bf(v.z), b3 = f2bf(v.w);
    ushort4 uv; uv.x=b0; uv.y=b1; uv.z=b2; uv.w=b3;
    *(ushort4*)&xb[(size_t)row*D + dd] = uv;
    tile[dd+0][n]=b0; tile[dd+1][n]=b1; tile[dd+2][n]=b2; tile[dd+3][n]=b3;
  }
  __syncthreads();
  int d = t & 127, hf = t >> 7;
  #pragma unroll
  for (int i=0;i<8;i++){
    short8 v = *(const short8*)&tile[d][hf*64 + i*8];
    *(short8*)&xbT[(size_t)d*N + nb + hf*64 + i*8] = v;
  }
}

// ---------------- MFMA GEMM: v = rs.*(A@W1+bias) + addin + (of2? : B@W2); of/ob/of2 outputs ----------------
__global__ __launch_bounds__(256) void k_gemm(
    const u16* __restrict__ A, const u16* __restrict__ W1T,
    const u16* __restrict__ B, const u16* __restrict__ W2T,
    const float* __restrict__ bias, const float* __restrict__ bias2,
    const float* __restrict__ rs, const float* __restrict__ addin,
    float* __restrict__ of, float* __restrict__ of2,
    u16* __restrict__ ob, float* __restrict__ csums, int N)
{
  __shared__ __align__(16) u16 Wsw[2][16384];
  const int t = threadIdx.x;
  const int w4 = t >> 6;
  const int lane = t & 63;
  const int l31 = lane & 31;
  const int hi = lane >> 5;
  const int rb = blockIdx.x * 32;

  #pragma unroll
  for (int i=0;i<8;i++){
    int slot = i*256 + t;
    int row = slot >> 4, g = slot & 15;
    short8 v = *(const short8*)(W1T + row*128 + g*8);
    *(short8*)((char*)&Wsw[0][0] + row*256 + ((g ^ (row&7))*16)) = v;
  }
  if (B){
    #pragma unroll
    for (int i=0;i<8;i++){
      int slot = i*256 + t;
      int row = slot >> 4, g = slot & 15;
      short8 v = *(const short8*)(W2T + row*128 + g*8);
      *(short8*)((char*)&Wsw[1][0] + row*256 + ((g ^ (row&7))*16)) = v;
    }
  }
  short8 af[8], bfr[8];
  #pragma unroll
  for (int g=0; g<8; g++)
    af[g] = *(const short8*)(A + (size_t)(rb + l31)*D + (2*g + hi)*8);
  if (B){
    #pragma unroll
    for (int g=0; g<8; g++)
      bfr[g] = *(const short8*)(B + (size_t)(rb + l31)*D + (2*g + hi)*8);
  }
  __syncthreads();

  f32x16 acc1, acc2;
  #pragma unroll
  for (int i=0;i<16;i++){ acc1[i]=0.f; acc2[i]=0.f; }
  const int wrow = w4*32 + l31;   // output column
  #pragma unroll
  for (int s=0;s<8;s++){
    int gr = 2*s + hi;
    short8 wf = *(const short8*)((const char*)&Wsw[0][0] + wrow*256 + ((gr ^ (wrow&7))*16));
    acc1 = __builtin_amdgcn_mfma_f32_32x32x16_bf16(af[s], wf, acc1, 0,0,0);
  }
  if (B){
    #pragma unroll
    for (int s=0;s<8;s++){
      int gr = 2*s + hi;
      short8 wf = *(const short8*)((const char*)&Wsw[1][0] + wrow*256 + ((gr ^ (wrow&7))*16));
      acc2 = __builtin_amdgcn_mfma_f32_32x32x16_bf16(bfr[s], wf, acc2, 0,0,0);
    }
  }
  const int col = wrow;
  float bv = bias ? bias[col] : 0.0f;
  float bv2 = bias2 ? bias2[col] : 0.0f;
  float ssum = 0.f, sq = 0.f;
  #pragma unroll
  for (int r=0;r<16;r++){
    int rr = (r&3) + 8*(r>>2) + 4*hi;
    size_t grow = (size_t)(rb + rr);
    float v = acc1[r] + bv;
    if (rs) v *= rs[grow];
    if (addin) v += addin[grow*D + col];
    if (B && !of2) v += acc2[r];
    if (of) of[grow*D + col] = v;
    if (ob) ob[grow*D + col] = f2bf(v);
    if (of2) of2[grow*D + col] = acc2[r] + bv2;
    ssum += v; sq += v*v;
  }
  if (csums){
    ssum += __shfl_xor(ssum, 32, 64);
    sq   += __shfl_xor(sq, 32, 64);
    if (hi == 0){
      atomicAdd(&csums[col], ssum);
      atomicAdd(&csums[128+col], sq);
    }
  }
}

// S[v] = sum over in-edges of hb[src] (bf16 in, f32 out)
__global__ __launch_bounds__(256) void k_gather(const u16* __restrict__ hb, const int* __restrict__ ptr,
                          const int* __restrict__ cnt, const int* __restrict__ srclist,
                          float* __restrict__ Sg, int N){
  int f = threadIdx.x & 127, sub = threadIdx.x >> 7;
  int v = blockIdx.x*2 + sub;
  if (v >= N) return;
  int b = ptr[v], n = cnt[v];
  float a0=0.f, a1=0.f, a2=0.f, a3=0.f;
  int j=0;
  for (; j+3<n; j+=4){
    int s0=srclist[b+j], s1=srclist[b+j+1], s2=srclist[b+j+2], s3=srclist[b+j+3];
    a0 += bf2f(hb[(size_t)s0*D + f]);
    a1 += bf2f(hb[(size_t)s1*D + f]);
    a2 += bf2f(hb[(size_t)s2*D + f]);
    a3 += bf2f(hb[(size_t)s3*D + f]);
  }
  for (; j<n; j++) a0 += bf2f(hb[(size_t)srclist[b+j]*D + f]);
  Sg[(size_t)v*D + f] = (a0+a1)+(a2+a3);
}

// ---------------- MFMA flash cross-attention: exp2-domain defer-max (r7-verified math), no setprio ----------------
__global__ __launch_bounds__(256, 2) void k_flash_mfma(
    const u16* __restrict__ xb, const u16* __restrict__ xbT,
    int N1, int N2, int Ntot,
    u16* __restrict__ Opartb, float* __restrict__ MLpart)
{
  __shared__ __align__(16) u16 Kbuf[2][4096];   // [32 key][128 d], granule^=(row&7)
  __shared__ __align__(16) u16 Vbuf[2][4096];   // [128 d][32 key], granule^=(d&3)

  const float L2E = 1.44269504f;
  const int t = threadIdx.x;
  const int w = t >> 6;
  const int lane = t & 63;
  const int l31 = lane & 31;
  const int hi = lane >> 5;

  const int qb = blockIdx.x / KVS;
  const int sp = blockIdx.x % KVS;
  const int qbase = qb * 128;
  const int qs = qbase + w*32;
  const bool isY = qbase >= N1;
  const int kv0 = isY ? 0 : N1;
  const int kvlen = isY ? N1 : N2;
  const int Lk = kvlen / KVS;
  const int kstart = kv0 + sp*Lk;
  const int ntiles = Lk >> 5;

  short8 qf[8];
  #pragma unroll
  for (int c = 0; c < 8; ++c)
    qf[c] = *(const short8*)(xb + (size_t)(qs + l31)*D + c*16 + hi*8);

  const int kr = t >> 3;
  const int kg = (t & 7) * 2;
  const int vd = t >> 1;
  const int vj = (t & 1) * 2;
  const int kw0 = kr*256 + ((kg     ^ (kr & 7))*16);
  const int kw1 = kr*256 + (((kg+1) ^ (kr & 7))*16);
  const int vw0 = vd*64  + (((vj     ^ vd) & 3)*16);
  const int vw1 = vd*64  + ((((vj+1) ^ vd) & 3)*16);

  f32x16 O[4];
  #pragma unroll
  for (int mt=0; mt<4; ++mt)
    #pragma unroll
    for (int i=0;i<16;i++) O[mt][i] = 0.f;
  float m_run = -3.0e38f, l_run = 0.0f;   // m_run in base-2 domain

  {
    int kb = kstart;
    short8 a0 = *(const short8*)(xb  + (size_t)(kb+kr)*D + kg*8);
    short8 a1 = *(const short8*)(xb  + (size_t)(kb+kr)*D + (kg+1)*8);
    short8 v0 = *(const short8*)(xbT + (size_t)vd*Ntot + kb + vj*8);
    short8 v1 = *(const short8*)(xbT + (size_t)vd*Ntot + kb + (vj+1)*8);
    *(short8*)((char*)&Kbuf[0][0] + kw0) = a0;
    *(short8*)((char*)&Kbuf[0][0] + kw1) = a1;
    *(short8*)((char*)&Vbuf[0][0] + vw0) = v0;
    *(short8*)((char*)&Vbuf[0][0] + vw1) = v1;
  }
  __syncthreads();

  for (int tt = 0; tt < ntiles; ++tt){
    const int cur = tt & 1;
    const int nxt = cur ^ 1;
    short8 a0, a1, v0, v1;
    const bool more = (tt+1 < ntiles);
    if (more){
      int kb = kstart + (tt+1)*32;
      a0 = *(const short8*)(xb  + (size_t)(kb+kr)*D + kg*8);
      a1 = *(const short8*)(xb  + (size_t)(kb+kr)*D + (kg+1)*8);
      v0 = *(const short8*)(xbT + (size_t)vd*Ntot + kb + vj*8);
      v1 = *(const short8*)(xbT + (size_t)vd*Ntot + kb + (vj+1)*8);
    }

    const char* Klds = (const char*)&Kbuf[cur][0];
    const char* Vlds = (const char*)&Vbuf[cur][0];

    // ---- S^T = K @ Q^T
    f32x16 sa, sb;
    #pragma unroll
    for (int i=0;i<16;i++){ sa[i]=0.f; sb[i]=0.f; }
    #pragma unroll
    for (int c = 0; c < 8; c += 2){
      int gr0 = 2*c + hi;
      short8 ka = *(const short8*)(Klds + l31*256 + ((gr0 ^ (l31&7))*16));
      sa = __builtin_amdgcn_mfma_f32_32x32x16_bf16(ka, qf[c], sa, 0,0,0);
      int gr1 = 2*(c+1) + hi;
      short8 kbf = *(const short8*)(Klds + l31*256 + ((gr1 ^ (l31&7))*16));
      sb = __builtin_amdgcn_mfma_f32_32x32x16_bf16(kbf, qf[c+1], sb, 0,0,0);
    }
    f32x16 s;
    #pragma unroll
    for (int i=0;i<16;i++) s[i] = sa[i] + sb[i];

    // ---- online softmax, base-2 domain, defer-max (r7-verified)
    float tm = s[0];
    #pragma unroll
    for (int i=1;i<16;i++) tm = fmaxf(tm, s[i]);
    tm = fmaxf(tm, __shfl_xor(tm, 32, 64));
    float tm2 = tm * L2E;
    if (__any(tm2 > m_run + 11.544f)){
      float mnew = fmaxf(m_run, tm2);
      float alpha = exp2f(m_run - mnew);
      l_run *= alpha;
      m_run = mnew;
      #pragma unroll
      for (int i=0;i<16;i++){ O[0][i]*=alpha; O[1][i]*=alpha; O[2][i]*=alpha; O[3][i]*=alpha; }
    }
    float rsum = 0.f;
    #pragma unroll
    for (int i=0;i<16;i++){ float p = exp2f(fmaf(s[i], L2E, -m_run)); s[i]=p; rsum += p; }
    rsum += __shfl_xor(rsum, 32, 64);
    l_run += rsum;

    // ---- pack P to bf16 pairs
    u32 pk[8];
    #pragma unroll
    for (int i=0;i<8;i++){
      u32 r;
      asm("v_cvt_pk_bf16_f32 %0, %1, %2" : "=v"(r) : "v"(s[2*i]), "v"(s[2*i+1]));
      pk[i] = r;
    }

    // ---- PV: O^T += V^T @ P^T
    #pragma unroll
    for (int ks=0; ks<2; ++ks){
      u32 send0 = hi ? pk[(2*ks)*2+0] : pk[(2*ks+1)*2+0];
      u32 send1 = hi ? pk[(2*ks)*2+1] : pk[(2*ks+1)*2+1];
      u32 xv0 = (u32)__shfl_xor((int)send0, 32, 64);
      u32 xv1 = (u32)__shfl_xor((int)send1, 32, 64);
      u32 own0 = hi ? pk[(2*ks+1)*2+0] : pk[(2*ks)*2+0];
      u32 own1 = hi ? pk[(2*ks+1)*2+1] : pk[(2*ks)*2+1];
      u32x4 bv;
      bv.x = hi ? xv0 : own0;
      bv.y = hi ? xv1 : own1;
      bv.z = hi ? own0 : xv0;
      bv.w = hi ? own1 : xv1;
      short8 pf = __builtin_bit_cast(short8, bv);
      #pragma unroll
      for (int mt=0; mt<4; ++mt){
        int dd = mt*32 + l31;
        int j = 2*ks + hi;
        short8 vf = *(const short8*)(Vlds + dd*64 + (((j ^ dd) & 3)*16));
        O[mt] = __builtin_amdgcn_mfma_f32_32x32x16_bf16(vf, pf, O[mt], 0,0,0);
      }
    }

    if (more){
      *(short8*)((char*)&Kbuf[nxt][0] + kw0) = a0;
      *(short8*)((char*)&Kbuf[nxt][0] + kw1) = a1;
      *(short8*)((char*)&Vbuf[nxt][0] + vw0) = v0;
      *(short8*)((char*)&Vbuf[nxt][0] + vw1) = v1;
    }
    __syncthreads();
  }

  const int strip = qs >> 5;
  u16* Od = Opartb + ((size_t)strip*KVS + sp)*4096;
  #pragma unroll
  for (int mt=0; mt<4; ++mt){
    #pragma unroll
    for (int r=0;r<16;r++){
      int dd = mt*32 + (r&3) + 8*(r>>2) + 4*hi;
      Od[dd*32 + l31] = f2bf(O[mt][r]);
    }
  }
  if (lane < 32){
    float* mlp = MLpart + ((size_t)strip*KVS + sp)*64;
    mlp[l31*2+0] = m_run;
    mlp[l31*2+1] = l_run;
  }
}

// ---------------- fused: fcomb (blocks < nstrips) + hm2 GEMM (blocks >= nstrips) ----------------
__global__ __launch_bounds__(256) void k_fcomb_hm2(
    const u16* __restrict__ Opartb, const float* __restrict__ MLpart,
    const float* __restrict__ x, u16* __restrict__ attinb,
    const u16* __restrict__ xb, const u16* __restrict__ W1T, const float* __restrict__ fb2,
    u16* __restrict__ hm2b, int nstrips, int N)
{
  // 32768 B: hm2 branch stages a full 128x256B swizzled weight tile (r10 bug: was 18432 -> OOB)
  __shared__ __align__(16) char smem[32768];
  const int t = threadIdx.x;
  if ((int)blockIdx.x < nstrips){
    // ---------- fcomb role: attinb = bf16(x - (sum_s w_s O_s)/L) ----------
    const int strip = blockIdx.x;
    float (*cw)[32] = (float(*)[32])smem;             // [KVS][32] = 1024 B
    float (*Tld)[33] = (float(*)[33])(smem + 1024);   // [128][33] = 16896 B
    if (t < 32){
      const float* mlp = MLpart + (size_t)strip*KVS*64;
      float mv[KVS], lv[KVS];
      float M = -3.0e38f;
      #pragma unroll
      for (int s2=0;s2<KVS;s2++){ mv[s2]=mlp[s2*64+t*2]; lv[s2]=mlp[s2*64+t*2+1]; M = fmaxf(M, mv[s2]); }
      float L = 0.f;
      #pragma unroll
      for (int s2=0;s2<KVS;s2++){ float wv=exp2f(mv[s2]-M); cw[s2][t]=wv; L += wv*lv[s2]; }
      float inv = 1.0f / L;
      #pragma unroll
      for (int s2=0;s2<KVS;s2++) cw[s2][t] *= inv;
    }
    __syncthreads();
    {
      const int d = t >> 1, q0 = (t & 1) * 16;
      const u16* Ob = Opartb + (size_t)strip*KVS*4096;
      float acc[16];
      #pragma unroll
      for (int j=0;j<16;j++) acc[j]=0.f;
      #pragma unroll
      for (int s2=0; s2<KVS; ++s2){
        const u16* row = Ob + s2*4096 + d*32 + q0;
        short8 v8a = *(const short8*)row;
        short8 v8b = *(const short8*)(row + 8);
        #pragma unroll
        for (int j=0;j<8;j++){
          acc[j]   += cw[s2][q0+j]  *bf2f((u16)v8a[j]);
          acc[8+j] += cw[s2][q0+8+j]*bf2f((u16)v8b[j]);
        }
      }
      #pragma unroll
      for (int j=0;j<16;j++) Tld[d][q0+j] = acc[j];
    }
    __syncthreads();
    {
      const int q = t >> 3, c0 = (t & 7) * 16;
      const size_t row = (size_t)(strip*32 + q)*D;
      #pragma unroll
      for (int i=0;i<16;i+=4){
        float4 xr = *(const float4*)&x[row + c0 + i];
        ushort4 o;
        o.x = f2bf(xr.x - Tld[c0+i+0][q]);
        o.y = f2bf(xr.y - Tld[c0+i+1][q]);
        o.z = f2bf(xr.z - Tld[c0+i+2][q]);
        o.w = f2bf(xr.w - Tld[c0+i+3][q]);
        *(ushort4*)&attinb[row + c0 + i] = o;
      }
    }
  } else {
    // ---------- hm2 GEMM role: hm2b = bf16(x@(Wn@Wm2) + fb2) ----------
    u16* Wsw = (u16*)smem;   // 128 rows x 256 B = 32768 B
    const int w4 = t >> 6;
    const int lane = t & 63;
    const int l31 = lane & 31;
    const int hi = lane >> 5;
    const int rb = ((int)blockIdx.x - nstrips) * 32;
    #pragma unroll
    for (int i=0;i<8;i++){
      int slot = i*256 + t;
      int row = slot >> 4, g = slot & 15;
      short8 v = *(const short8*)(W1T + row*128 + g*8);
      *(short8*)((char*)Wsw + row*256 + ((g ^ (row&7))*16)) = v;
    }
    short8 af[8];
    #pragma unroll
    for (int g=0; g<8; g++)
      af[g] = *(const short8*)(xb + (size_t)(rb + l31)*D + (2*g + hi)*8);
    __syncthreads();
    f32x16 acc1;
    #pragma unroll
    for (int i=0;i<16;i++) acc1[i]=0.f;
    const int wrow = w4*32 + l31;
    #pragma unroll
    for (int s=0;s<8;s++){
      int gr = 2*s + hi;
      short8 wf = *(const short8*)((const char*)Wsw + wrow*256 + ((gr ^ (wrow&7))*16));
      acc1 = __builtin_amdgcn_mfma_f32_32x32x16_bf16(af[s], wf, acc1, 0,0,0);
    }
    float bv = fb2[wrow];
    #pragma unroll
    for (int r=0;r<16;r++){
      int rr = (r&3) + 8*(r>>2) + 4*hi;
      hm2b[(size_t)(rb + rr)*D + wrow] = f2bf(acc1[r] + bv);
    }
  }
}

// ---------------- norm + f32/bf16/bf16T write fused ----------------
__global__ __launch_bounds__(256) void k_normcvt(const float* __restrict__ outb,
                        const float* __restrict__ sums,
                        const float* __restrict__ gamma, const float* __restrict__ beta,
                        int N, float* __restrict__ x, u16* __restrict__ xb, u16* __restrict__ xbT){
  __shared__ u16 tile[128][136];
  __shared__ float smu[128], srs[128], sg2[128], sb2[128];
  int t = threadIdx.x;
  if (t < 128){
    float mu = sums[t] / (float)N;
    float var = fmaxf(sums[128+t]/(float)N - mu*mu, 0.0f);
    smu[t]=mu; srs[t]=rsqrtf(var + 1e-5f);
    sg2[t]=gamma[t]; sb2[t]=beta[t];
  }
  __syncthreads();
  int nb = blockIdx.x * 128;
  int n = t >> 1, ch = t & 1;
  #pragma unroll
  for (int i=0;i<16;i++){
    int dd = ch*64 + i*4;
    float4 v = *(const float4*)&outb[(size_t)(nb+n)*D + dd];
    float4 y;
    y.x = (v.x - smu[dd+0])*srs[dd+0]*sg2[dd+0] + sb2[dd+0];
    y.y = (v.y - smu[dd+1])*srs[dd+1]*sg2[dd+1] + sb2[dd+1];
    y.z = (v.z - smu[dd+2])*srs[dd+2]*sg2[dd+2] + sb2[dd+2];
    y.w = (v.w - smu[dd+3])*srs[dd+3]*sg2[dd+3] + sb2[dd+3];
    *(float4*)&x[(size_t)(nb+n)*D + dd] = y;
    u16 b0=f2bf(y.x), b1=f2bf(y.y), b2=f2bf(y.z), b3=f2bf(y.w);
    ushort4 uv; uv.x=b0; uv.y=b1; uv.z=b2; uv.w=b3;
    *(ushort4*)&xb[(size_t)(nb+n)*D + dd] = uv;
    tile[dd+0][n]=b0; tile[dd+1][n]=b1; tile[dd+2][n]=b2; tile[dd+3][n]=b3;
  }
  __syncthreads();
  int d = t & 127, hf = t >> 7;
  #pragma unroll
  for (int i=0;i<8;i++){
    short8 v = *(const short8*)&tile[d][hf*64 + i*8];
    *(short8*)&xbT[(size_t)d*N + nb + hf*64 + i*8] = v;
  }
}

// ---------------- gated readout ----------------
__global__ __launch_bounds__(256) void k_gatepool(
    const float* __restrict__ states, const float* __restrict__ glog,
    int N1, int N, float* __restrict__ gsums)
{
  __shared__ float part[256];
  part[threadIdx.x] = 0.f;
  __syncthreads();
  int wid = threadIdx.x >> 6, lane = threadIdx.x & 63;
  for (int v = blockIdx.x*4 + wid; v < N; v += gridDim.x*4){
    float a0 = glog[(size_t)v*D + lane], a1 = glog[(size_t)v*D + lane + 64];
    float mx = fmaxf(a0,a1);
    #pragma unroll
    for (int off=32; off; off>>=1) mx = fmaxf(mx, __shfl_xor(mx, off, 64));
    float e0 = __expf(a0-mx), e1 = __expf(a1-mx);
    float ss = e0+e1;
    #pragma unroll
    for (int off=32; off; off>>=1) ss += __shfl_xor(ss, off, 64);
    float inv = 1.f/ss;
    int g = (v < N1) ? 0 : 1;
    atomicAdd(&part[g*128 + lane], states[(size_t)v*D+lane]*e0*inv);
    atomicAdd(&part[g*128 + lane + 64], states[(size_t)v*D+lane+64]*e1*inv);
  }
  __syncthreads();
  atomicAdd(&gsums[threadIdx.x], part[threadIdx.x]);
}

__global__ __launch_bounds__(256) void k_emb(
    const float* __restrict__ gsums, const float* __restrict__ Wf,
    const float* __restrict__ bf_, int N1, int N2, float* __restrict__ outp)
{
  __shared__ float mean[256];
  int t = threadIdx.x;
  mean[t] = gsums[t] / ((t < 128) ? (float)N1 : (float)N2);
  __syncthreads();
  int g = t >> 7, dc = t & 127;
  float acc = bf_[dc];
  for (int k=0;k<D;k++) acc += mean[g*128 + k] * Wf[k*D + dc];
  outp[t] = acc;
}

extern "C" void kernel_launch(void* const* d_in, const int* in_sizes, int n_in,
                              void* d_out, int out_size, void* d_ws, size_t ws_size,
                              hipStream_t stream) {
  const float* feats1 = (const float*)d_in[0];
  const int*   ei1    = (const int*)d_in[1];
  const float* feats2 = (const float*)d_in[2];
  const int*   ei2    = (const int*)d_in[3];
  const float* Wn = (const float*)d_in[6];
  const float* bn = (const float*)d_in[7];
  const float* Wm = (const float*)d_in[8];
  const float* bm = (const float*)d_in[9];
  const float* Wp = (const float*)d_in[10];
  const float* bp = (const float*)d_in[11];
  const float* gamma = (const float*)d_in[12];
  const float* beta  = (const float*)d_in[13];
  const float* Wa = (const float*)d_in[14];
  const float* ba = (const float*)d_in[15];
  const float* Wg = (const float*)d_in[16];
  const float* bg = (const float*)d_in[17];
  const float* Wf = (const float*)d_in[18];
  const float* bff = (const float*)d_in[19];

  int N1 = in_sizes[0]/D, E1 = in_sizes[1]/2;
  int N2 = in_sizes[2]/D, E2 = in_sizes[3]/2;
  int N = N1+N2;
  int nstrips = N/32;

  char* w = (char*)d_ws;
  float* x    = (float*)w; w += (size_t)N*D*4;
  u16* xb     = (u16*)w;   w += (size_t)N*D*2;
  u16* xbT    = (u16*)w;   w += (size_t)N*D*2;
  u16* hm2b   = (u16*)w;   w += (size_t)N*D*2;
  u16* aggrb  = (u16*)w;   w += (size_t)N*D*2;
  u16* attinb = (u16*)w;   w += (size_t)N*D*2;
  // contiguous zero-init region: cnt | sums(3x256) | gsums(256)
  int* cnt    = (int*)w;   w += (size_t)N*4;
  float* sums = (float*)w; w += 3*256*4;
  float* gsums= (float*)w; w += 256*4;
  int* ptr    = (int*)w;   w += (size_t)N*4;
  int* cursor = (int*)w;   w += (size_t)N*4;
  float* degf = (float*)w; w += (size_t)N*4;
  int* srclist= (int*)w;   w += (size_t)(E1+E2)*4;
  u16* wgt    = (u16*)w;   w += (size_t)8*16384*2;
  u16* wfu    = (u16*)w;   w += (size_t)6*16384*2;
  float* fbias= (float*)w; w += (size_t)6*128*4;
  u16* Opartb = (u16*)w;   w += (size_t)nstrips*KVS*4096*2;
  float* MLpart=(float*)w; w += (size_t)nstrips*KVS*64*4;
  // lifetime-disjoint f32 aliases inside Opartb:
  float* Sg     = (float*)Opartb;
  float* outb   = (float*)Opartb + (size_t)N*D;
  float* states = Sg;
  float* glog   = outb;

  hipMemsetAsync(cnt, 0, (size_t)N*4 + 4*256*4, stream);
  k_count<<<1024,256,0,stream>>>(ei1, ei2, E1, E2, N1, cnt);
  k_scan<<<1,256,0,stream>>>(cnt, ptr, cursor, degf, N);
  k_fill<<<1024,256,0,stream>>>(ei1, ei2, E1, E2, N1, cursor, srclist);
  k_wcvt<<<8,256,0,stream>>>(Wp, Wa, Wg, wgt);
  k_wfuse<<<6,256,0,stream>>>(Wn, Wm, bn, bm, wfu, fbias);
  k_cvt0<<<N/128,256,0,stream>>>(feats1, feats2, N1, x, xb, xbT, N);

  for (int l=0;l<3;l++){
    const u16* fuse2T_l = wfu + (size_t)l*16384;
    const u16* fuse1T_l = wfu + (size_t)(3+l)*16384;
    const float* fb2_l  = fbias + (size_t)l*128;
    const float* fb1_l  = fbias + (size_t)(3+l)*128;
    const u16* Wp1T_l = wgt + (size_t)(0+l)*16384;
    const u16* Wp2T_l = wgt + (size_t)(3+l)*16384;
    const float* bp_l = bp + (size_t)l*D;
    float* sums_l = sums + (size_t)l*256;

    k_flash_mfma<<<(N/128)*KVS,256,0,stream>>>(xb, xbT, N1, N2, N, Opartb, MLpart);
    // fused: fcomb (attinb) + hm2 GEMM
    k_fcomb_hm2<<<nstrips + N/32,256,0,stream>>>(Opartb, MLpart, x, attinb,
                                                 xb, fuse2T_l, fb2_l, hm2b, nstrips, N);
    k_gather<<<N/2,256,0,stream>>>(hm2b, ptr, cnt, srclist, Sg, N);
    // aggr = deg.*(x@(Wn@Wm1) + fb1) + Sg
    k_gemm<<<N/32,256,0,stream>>>(xb, fuse1T_l, nullptr, nullptr, fb1_l, nullptr,
                                  degf, Sg, nullptr, nullptr, aggrb, nullptr, N);
    // outb = aggr@Wp_top + attin@Wp_bot + bp (f32 out, fused column sums)
    k_gemm<<<N/32,256,0,stream>>>(aggrb, Wp1T_l, attinb, Wp2T_l, bp_l, nullptr,
                                  nullptr, nullptr, outb, nullptr, nullptr, sums_l, N);
    k_normcvt<<<N/128,256,0,stream>>>(outb, sums_l, gamma + (size_t)l*D, beta + (size_t)l*D, N, x, xb, xbT);
  }

  // readout: states = x@Wa+ba, glog = x@Wg+bg in one dual-output GEMM
  k_gemm<<<N/32,256,0,stream>>>(xb, wgt + (size_t)6*16384, xb, wgt + (size_t)7*16384,
                                ba, bg, nullptr, nullptr, states, glog, nullptr, nullptr, N);
  k_gatepool<<<64,256,0,stream>>>(states, glog, N1, N, gsums);
  k_emb<<<1,256,0,stream>>>(gsums, Wf, bff, N1, N2, (float*)d_out);
}

// Round 12
// 634.562 us; speedup vs baseline: 1.2650x; 1.0353x over previous
//
#include <hip/hip_runtime.h>
#include <hip/hip_bf16.h>

#define D 128
#define KVS 16
typedef unsigned short u16;
typedef unsigned int u32;
typedef __attribute__((ext_vector_type(8))) short short8;
typedef __attribute__((ext_vector_type(16))) float f32x16;
typedef __attribute__((ext_vector_type(4))) u32 u32x4;

__device__ __forceinline__ u16 f2bf(float f){
  u32 u = __builtin_bit_cast(u32, f);
  u32 r = (u + 0x7FFFu + ((u >> 16) & 1u)) >> 16;
  return (u16)r;
}
__device__ __forceinline__ float bf2f(u16 u){
  union { u32 i; float f; } v; v.i = ((u32)u) << 16; return v.f;
}

// ---------------- CSR build ----------------
__global__ void k_count(const int* __restrict__ ei1, const int* __restrict__ ei2,
                        int E1, int E2, int N1, int* __restrict__ cnt){
  int i = blockIdx.x*blockDim.x + threadIdx.x;
  int Et = E1 + E2;
  for (; i < Et; i += gridDim.x*blockDim.x){
    int dst = (i < E1) ? ei1[E1 + i] : (ei2[E2 + (i - E1)] + N1);
    atomicAdd(&cnt[dst], 1);
  }
}

__global__ void k_scan(const int* __restrict__ cnt, int* __restrict__ ptr,
                       int* __restrict__ cursor, float* __restrict__ degf, int N){
  __shared__ int part[256];
  int t = threadIdx.x;
  int per = (N + 255) >> 8;
  int lo = t*per, hi = min(N, lo+per);
  int s = 0;
  for (int j=lo;j<hi;j++) s += cnt[j];
  part[t] = s; __syncthreads();
  if (t==0){ int acc=0; for (int j=0;j<256;j++){ int v=part[j]; part[j]=acc; acc+=v; } }
  __syncthreads();
  int acc = part[t];
  for (int j=lo;j<hi;j++){ ptr[j]=acc; cursor[j]=acc; degf[j]=(float)cnt[j]; acc += cnt[j]; }
}

__global__ void k_fill(const int* __restrict__ ei1, const int* __restrict__ ei2,
                       int E1, int E2, int N1, int* __restrict__ cursor, int* __restrict__ srclist){
  int i = blockIdx.x*blockDim.x + threadIdx.x;
  int Et = E1 + E2;
  for (; i < Et; i += gridDim.x*blockDim.x){
    int src, dst;
    if (i < E1){ src = ei1[i]; dst = ei1[E1+i]; }
    else { int j = i - E1; src = ei2[j] + N1; dst = ei2[E2+j] + N1; }
    int p = atomicAdd(&cursor[dst], 1);
    srclist[p] = src;
  }
}

// ---------------- merged prologue: wcvt (blocks 0..7) | wfuse (8..13) | cvt0 (14..) ----------------
__global__ __launch_bounds__(256) void k_prep(
    const float* __restrict__ Wp, const float* __restrict__ Wa, const float* __restrict__ Wg,
    const float* __restrict__ Wn, const float* __restrict__ Wm,
    const float* __restrict__ bn, const float* __restrict__ bm,
    const float* __restrict__ src1, const float* __restrict__ src2, int N1,
    u16* __restrict__ wgt, u16* __restrict__ wfu, float* __restrict__ fbias,
    float* __restrict__ x, u16* __restrict__ xb, u16* __restrict__ xbT, int N)
{
  __shared__ u16 tile[128][136];
  const int m = blockIdx.x;
  const int t = threadIdx.x;
  if (m < 8){
    // ---- wcvt: f32 [128k][128n] -> bf16 transposed [128n][128k]
    const float* src; u16* dst;
    if (m < 6){ int l = m % 3, half = m / 3; src = Wp + (size_t)l*32768 + half*16384; dst = wgt + (size_t)(half*3 + l)*16384; }
    else if (m == 6){ src = Wa; dst = wgt + (size_t)6*16384; }
    else { src = Wg; dst = wgt + (size_t)7*16384; }
    int n = t & 127, rh = t >> 7;
    for (int r0=0; r0<128; r0+=2){
      int r = r0 + rh;
      tile[n][r] = f2bf(src[r*128 + n]);
    }
    __syncthreads();
    int row = t >> 1, ch = t & 1;
    #pragma unroll
    for (int i=0;i<4;i++){
      int k0 = ch*64 + i*16;
      short8 a = *(const short8*)&tile[row][k0];
      short8 b = *(const short8*)&tile[row][k0+8];
      *(short8*)&dst[row*128 + k0] = a;
      *(short8*)&dst[row*128 + k0 + 8] = b;
    }
  } else if (m < 14){
    // ---- wfuse: wfu[l]=(Wn_l@Wm2_l)^T, wfu[3+l]=(Wn_l@Wm1_l)^T + fused biases
    int blk = m - 8;
    int l = blk % 3, which = blk / 3;
    const float* A  = Wn + (size_t)l*16384;
    const float* Bm = Wm + (size_t)l*32768 + (which==0 ? 16384 : 0);
    u16* dst  = wfu  + (size_t)(which==0 ? l : 3+l)*16384;
    float* fb = fbias + (size_t)(which==0 ? l : 3+l)*128;
    int c0 = (t & 31) * 4;
    int r0 = (t >> 5) * 16;
    float acc[16][4];
    #pragma unroll
    for (int i=0;i<16;i++){ acc[i][0]=0.f; acc[i][1]=0.f; acc[i][2]=0.f; acc[i][3]=0.f; }
    for (int k=0;k<128;k++){
      float4 b4 = *(const float4*)&Bm[k*128 + c0];
      #pragma unroll
      for (int i=0;i<16;i++){
        float a = A[(r0+i)*128 + k];
        acc[i][0] += a*b4.x; acc[i][1] += a*b4.y; acc[i][2] += a*b4.z; acc[i][3] += a*b4.w;
      }
    }
    #pragma unroll
    for (int i=0;i<16;i++)
      #pragma unroll
      for (int j=0;j<4;j++)
        dst[(size_t)(c0+j)*128 + (r0+i)] = f2bf(acc[i][j]);
    if (t < 128){
      float s = 0.f;
      for (int k=0;k<128;k++) s += bn[l*128+k]*Bm[k*128+t];
      if (which) s += bm[l*128+t];
      fb[t] = s;
    }
  } else {
    // ---- cvt0: feats -> x (f32), xb [N][128], xbT [128][N]
    int nb = (m - 14) * 128;
    int n = t >> 1, ch = t & 1;
    int row = nb + n;
    const float* srow = (row < N1) ? &src1[(size_t)row*D] : &src2[(size_t)(row-N1)*D];
    #pragma unroll
    for (int i=0;i<16;i++){
      int dd = ch*64 + i*4;
      float4 v = *(const float4*)&srow[dd];
      *(float4*)&x[(size_t)row*D + dd] = v;
      u16 b0 = f2bf(v.x), b1 = f2bf(v.y), b2 = f2bf(v.z), b3 = f2bf(v.w);
      ushort4 uv; uv.x=b0; uv.y=b1; uv.z=b2; uv.w=b3;
      *(ushort4*)&xb[(size_t)row*D + dd] = uv;
      tile[dd+0][n]=b0; tile[dd+1][n]=b1; tile[dd+2][n]=b2; tile[dd+3][n]=b3;
    }
    __syncthreads();
    int d = t & 127, hf = t >> 7;
    #pragma unroll
    for (int i=0;i<8;i++){
      short8 v = *(const short8*)&tile[d][hf*64 + i*8];
      *(short8*)&xbT[(size_t)d*N + nb + hf*64 + i*8] = v;
    }
  }
}

// ---------------- MFMA GEMM: v = rs.*(A@W1+bias) + addin + (of2? : B@W2); of/ob/of2 outputs ----------------
__global__ __launch_bounds__(256) void k_gemm(
    const u16* __restrict__ A, const u16* __restrict__ W1T,
    const u16* __restrict__ B, const u16* __restrict__ W2T,
    const float* __restrict__ bias, const float* __restrict__ bias2,
    const float* __restrict__ rs, const float* __restrict__ addin,
    float* __restrict__ of, float* __restrict__ of2,
    u16* __restrict__ ob, float* __restrict__ csums, int N)
{
  __shared__ __align__(16) u16 Wsw[2][16384];
  const int t = threadIdx.x;
  const int w4 = t >> 6;
  const int lane = t & 63;
  const int l31 = lane & 31;
  const int hi = lane >> 5;
  const int rb = blockIdx.x * 32;

  #pragma unroll
  for (int i=0;i<8;i++){
    int slot = i*256 + t;
    int row = slot >> 4, g = slot & 15;
    short8 v = *(const short8*)(W1T + row*128 + g*8);
    *(short8*)((char*)&Wsw[0][0] + row*256 + ((g ^ (row&7))*16)) = v;
  }
  if (B){
    #pragma unroll
    for (int i=0;i<8;i++){
      int slot = i*256 + t;
      int row = slot >> 4, g = slot & 15;
      short8 v = *(const short8*)(W2T + row*128 + g*8);
      *(short8*)((char*)&Wsw[1][0] + row*256 + ((g ^ (row&7))*16)) = v;
    }
  }
  short8 af[8], bfr[8];
  #pragma unroll
  for (int g=0; g<8; g++)
    af[g] = *(const short8*)(A + (size_t)(rb + l31)*D + (2*g + hi)*8);
  if (B){
    #pragma unroll
    for (int g=0; g<8; g++)
      bfr[g] = *(const short8*)(B + (size_t)(rb + l31)*D + (2*g + hi)*8);
  }
  __syncthreads();

  f32x16 acc1, acc2;
  #pragma unroll
  for (int i=0;i<16;i++){ acc1[i]=0.f; acc2[i]=0.f; }
  const int wrow = w4*32 + l31;   // output column
  #pragma unroll
  for (int s=0;s<8;s++){
    int gr = 2*s + hi;
    short8 wf = *(const short8*)((const char*)&Wsw[0][0] + wrow*256 + ((gr ^ (wrow&7))*16));
    acc1 = __builtin_amdgcn_mfma_f32_32x32x16_bf16(af[s], wf, acc1, 0,0,0);
  }
  if (B){
    #pragma unroll
    for (int s=0;s<8;s++){
      int gr = 2*s + hi;
      short8 wf = *(const short8*)((const char*)&Wsw[1][0] + wrow*256 + ((gr ^ (wrow&7))*16));
      acc2 = __builtin_amdgcn_mfma_f32_32x32x16_bf16(bfr[s], wf, acc2, 0,0,0);
    }
  }
  const int col = wrow;
  float bv = bias ? bias[col] : 0.0f;
  float bv2 = bias2 ? bias2[col] : 0.0f;
  float ssum = 0.f, sq = 0.f;
  #pragma unroll
  for (int r=0;r<16;r++){
    int rr = (r&3) + 8*(r>>2) + 4*hi;
    size_t grow = (size_t)(rb + rr);
    float v = acc1[r] + bv;
    if (rs) v *= rs[grow];
    if (addin) v += addin[grow*D + col];
    if (B && !of2) v += acc2[r];
    if (of) of[grow*D + col] = v;
    if (ob) ob[grow*D + col] = f2bf(v);
    if (of2) of2[grow*D + col] = acc2[r] + bv2;
    ssum += v; sq += v*v;
  }
  if (csums){
    ssum += __shfl_xor(ssum, 32, 64);
    sq   += __shfl_xor(sq, 32, 64);
    if (hi == 0){
      atomicAdd(&csums[col], ssum);
      atomicAdd(&csums[128+col], sq);
    }
  }
}

// S[v] = sum over in-edges of hb[src] (bf16 in, f32 out)
__global__ __launch_bounds__(256) void k_gather(const u16* __restrict__ hb, const int* __restrict__ ptr,
                          const int* __restrict__ cnt, const int* __restrict__ srclist,
                          float* __restrict__ Sg, int N){
  int f = threadIdx.x & 127, sub = threadIdx.x >> 7;
  int v = blockIdx.x*2 + sub;
  if (v >= N) return;
  int b = ptr[v], n = cnt[v];
  float a0=0.f, a1=0.f, a2=0.f, a3=0.f;
  int j=0;
  for (; j+3<n; j+=4){
    int s0=srclist[b+j], s1=srclist[b+j+1], s2=srclist[b+j+2], s3=srclist[b+j+3];
    a0 += bf2f(hb[(size_t)s0*D + f]);
    a1 += bf2f(hb[(size_t)s1*D + f]);
    a2 += bf2f(hb[(size_t)s2*D + f]);
    a3 += bf2f(hb[(size_t)s3*D + f]);
  }
  for (; j<n; j++) a0 += bf2f(hb[(size_t)srclist[b+j]*D + f]);
  Sg[(size_t)v*D + f] = (a0+a1)+(a2+a3);
}

// ---------------- MFMA flash cross-attention: exp2-domain defer-max, single acc chain, KVS=16 ----------------
__global__ __launch_bounds__(256, 2) void k_flash_mfma(
    const u16* __restrict__ xb, const u16* __restrict__ xbT,
    int N1, int N2, int Ntot,
    u16* __restrict__ Opartb, float* __restrict__ MLpart)
{
  __shared__ __align__(16) u16 Kbuf[2][4096];   // [32 key][128 d], granule^=(row&7)
  __shared__ __align__(16) u16 Vbuf[2][4096];   // [128 d][32 key], granule^=(d&3)

  const float L2E = 1.44269504f;
  const int t = threadIdx.x;
  const int w = t >> 6;
  const int lane = t & 63;
  const int l31 = lane & 31;
  const int hi = lane >> 5;

  const int qb = blockIdx.x / KVS;
  const int sp = blockIdx.x % KVS;
  const int qbase = qb * 128;
  const int qs = qbase + w*32;
  const bool isY = qbase >= N1;
  const int kv0 = isY ? 0 : N1;
  const int kvlen = isY ? N1 : N2;
  const int Lk = kvlen / KVS;
  const int kstart = kv0 + sp*Lk;
  const int ntiles = Lk >> 5;

  short8 qf[8];
  #pragma unroll
  for (int c = 0; c < 8; ++c)
    qf[c] = *(const short8*)(xb + (size_t)(qs + l31)*D + c*16 + hi*8);

  const int kr = t >> 3;
  const int kg = (t & 7) * 2;
  const int vd = t >> 1;
  const int vj = (t & 1) * 2;
  const int kw0 = kr*256 + ((kg     ^ (kr & 7))*16);
  const int kw1 = kr*256 + (((kg+1) ^ (kr & 7))*16);
  const int vw0 = vd*64  + (((vj     ^ vd) & 3)*16);
  const int vw1 = vd*64  + ((((vj+1) ^ vd) & 3)*16);

  f32x16 O[4];
  #pragma unroll
  for (int mt=0; mt<4; ++mt)
    #pragma unroll
    for (int i=0;i<16;i++) O[mt][i] = 0.f;
  float m_run = -3.0e38f, l_run = 0.0f;   // m_run in base-2 domain

  {
    int kb = kstart;
    short8 a0 = *(const short8*)(xb  + (size_t)(kb+kr)*D + kg*8);
    short8 a1 = *(const short8*)(xb  + (size_t)(kb+kr)*D + (kg+1)*8);
    short8 v0 = *(const short8*)(xbT + (size_t)vd*Ntot + kb + vj*8);
    short8 v1 = *(const short8*)(xbT + (size_t)vd*Ntot + kb + (vj+1)*8);
    *(short8*)((char*)&Kbuf[0][0] + kw0) = a0;
    *(short8*)((char*)&Kbuf[0][0] + kw1) = a1;
    *(short8*)((char*)&Vbuf[0][0] + vw0) = v0;
    *(short8*)((char*)&Vbuf[0][0] + vw1) = v1;
  }
  __syncthreads();

  for (int tt = 0; tt < ntiles; ++tt){
    const int cur = tt & 1;
    const int nxt = cur ^ 1;
    short8 a0, a1, v0, v1;
    const bool more = (tt+1 < ntiles);
    if (more){
      int kb = kstart + (tt+1)*32;
      a0 = *(const short8*)(xb  + (size_t)(kb+kr)*D + kg*8);
      a1 = *(const short8*)(xb  + (size_t)(kb+kr)*D + (kg+1)*8);
      v0 = *(const short8*)(xbT + (size_t)vd*Ntot + kb + vj*8);
      v1 = *(const short8*)(xbT + (size_t)vd*Ntot + kb + (vj+1)*8);
    }

    const char* Klds = (const char*)&Kbuf[cur][0];
    const char* Vlds = (const char*)&Vbuf[cur][0];

    // ---- S^T = K @ Q^T (single accumulator chain)
    f32x16 s;
    #pragma unroll
    for (int i=0;i<16;i++) s[i]=0.f;
    #pragma unroll
    for (int c = 0; c < 8; ++c){
      int gr = 2*c + hi;
      short8 ka = *(const short8*)(Klds + l31*256 + ((gr ^ (l31&7))*16));
      s = __builtin_amdgcn_mfma_f32_32x32x16_bf16(ka, qf[c], s, 0,0,0);
    }

    // ---- online softmax, base-2 domain, defer-max
    float tm = s[0];
    #pragma unroll
    for (int i=1;i<16;i++) tm = fmaxf(tm, s[i]);
    tm = fmaxf(tm, __shfl_xor(tm, 32, 64));
    float tm2 = tm * L2E;
    if (__any(tm2 > m_run + 11.544f)){
      float mnew = fmaxf(m_run, tm2);
      float alpha = exp2f(m_run - mnew);
      l_run *= alpha;
      m_run = mnew;
      #pragma unroll
      for (int i=0;i<16;i++){ O[0][i]*=alpha; O[1][i]*=alpha; O[2][i]*=alpha; O[3][i]*=alpha; }
    }
    float rsum = 0.f;
    #pragma unroll
    for (int i=0;i<16;i++){ float p = exp2f(fmaf(s[i], L2E, -m_run)); s[i]=p; rsum += p; }
    rsum += __shfl_xor(rsum, 32, 64);
    l_run += rsum;

    // ---- pack P to bf16 pairs
    u32 pk[8];
    #pragma unroll
    for (int i=0;i<8;i++){
      u32 r;
      asm("v_cvt_pk_bf16_f32 %0, %1, %2" : "=v"(r) : "v"(s[2*i]), "v"(s[2*i+1]));
      pk[i] = r;
    }

    // ---- PV: O^T += V^T @ P^T
    #pragma unroll
    for (int ks=0; ks<2; ++ks){
      u32 send0 = hi ? pk[(2*ks)*2+0] : pk[(2*ks+1)*2+0];
      u32 send1 = hi ? pk[(2*ks)*2+1] : pk[(2*ks+1)*2+1];
      u32 xv0 = (u32)__shfl_xor((int)send0, 32, 64);
      u32 xv1 = (u32)__shfl_xor((int)send1, 32, 64);
      u32 own0 = hi ? pk[(2*ks+1)*2+0] : pk[(2*ks)*2+0];
      u32 own1 = hi ? pk[(2*ks+1)*2+1] : pk[(2*ks)*2+1];
      u32x4 bv;
      bv.x = hi ? xv0 : own0;
      bv.y = hi ? xv1 : own1;
      bv.z = hi ? own0 : xv0;
      bv.w = hi ? own1 : xv1;
      short8 pf = __builtin_bit_cast(short8, bv);
      #pragma unroll
      for (int mt=0; mt<4; ++mt){
        int dd = mt*32 + l31;
        int j = 2*ks + hi;
        short8 vf = *(const short8*)(Vlds + dd*64 + (((j ^ dd) & 3)*16));
        O[mt] = __builtin_amdgcn_mfma_f32_32x32x16_bf16(vf, pf, O[mt], 0,0,0);
      }
    }

    if (more){
      *(short8*)((char*)&Kbuf[nxt][0] + kw0) = a0;
      *(short8*)((char*)&Kbuf[nxt][0] + kw1) = a1;
      *(short8*)((char*)&Vbuf[nxt][0] + vw0) = v0;
      *(short8*)((char*)&Vbuf[nxt][0] + vw1) = v1;
    }
    __syncthreads();
  }

  const int strip = qs >> 5;
  u16* Od = Opartb + ((size_t)strip*KVS + sp)*4096;
  #pragma unroll
  for (int mt=0; mt<4; ++mt){
    #pragma unroll
    for (int r=0;r<16;r++){
      int dd = mt*32 + (r&3) + 8*(r>>2) + 4*hi;
      Od[dd*32 + l31] = f2bf(O[mt][r]);
    }
  }
  if (lane < 32){
    float* mlp = MLpart + ((size_t)strip*KVS + sp)*64;
    mlp[l31*2+0] = m_run;
    mlp[l31*2+1] = l_run;
  }
}

// ---------------- fused: fcomb (blocks < nstrips) + hm2 GEMM (blocks >= nstrips) ----------------
__global__ __launch_bounds__(256) void k_fcomb_hm2(
    const u16* __restrict__ Opartb, const float* __restrict__ MLpart,
    const float* __restrict__ x, u16* __restrict__ attinb,
    const u16* __restrict__ xb, const u16* __restrict__ W1T, const float* __restrict__ fb2,
    u16* __restrict__ hm2b, int nstrips, int N)
{
  // 32768 B: hm2 branch stages a full 128x256B swizzled weight tile
  __shared__ __align__(16) char smem[32768];
  const int t = threadIdx.x;
  if ((int)blockIdx.x < nstrips){
    // ---------- fcomb role: attinb = bf16(x - (sum_s w_s O_s)/L) ----------
    const int strip = blockIdx.x;
    float (*cw)[32] = (float(*)[32])smem;             // [KVS][32] = 2048 B
    float (*Tld)[33] = (float(*)[33])(smem + 2048);   // [128][33] = 16896 B
    if (t < 32){
      const float* mlp = MLpart + (size_t)strip*KVS*64;
      float mv[KVS], lv[KVS];
      float M = -3.0e38f;
      #pragma unroll
      for (int s2=0;s2<KVS;s2++){ mv[s2]=mlp[s2*64+t*2]; lv[s2]=mlp[s2*64+t*2+1]; M = fmaxf(M, mv[s2]); }
      float L = 0.f;
      #pragma unroll
      for (int s2=0;s2<KVS;s2++){ float wv=exp2f(mv[s2]-M); cw[s2][t]=wv; L += wv*lv[s2]; }
      float inv = 1.0f / L;
      #pragma unroll
      for (int s2=0;s2<KVS;s2++) cw[s2][t] *= inv;
    }
    __syncthreads();
    {
      const int d = t >> 1, q0 = (t & 1) * 16;
      const u16* Ob = Opartb + (size_t)strip*KVS*4096;
      float acc[16];
      #pragma unroll
      for (int j=0;j<16;j++) acc[j]=0.f;
      #pragma unroll
      for (int s2=0; s2<KVS; ++s2){
        const u16* row = Ob + s2*4096 + d*32 + q0;
        short8 v8a = *(const short8*)row;
        short8 v8b = *(const short8*)(row + 8);
        #pragma unroll
        for (int j=0;j<8;j++){
          acc[j]   += cw[s2][q0+j]  *bf2f((u16)v8a[j]);
          acc[8+j] += cw[s2][q0+8+j]*bf2f((u16)v8b[j]);
        }
      }
      #pragma unroll
      for (int j=0;j<16;j++) Tld[d][q0+j] = acc[j];
    }
    __syncthreads();
    {
      const int q = t >> 3, c0 = (t & 7) * 16;
      const size_t row = (size_t)(strip*32 + q)*D;
      #pragma unroll
      for (int i=0;i<16;i+=4){
        float4 xr = *(const float4*)&x[row + c0 + i];
        ushort4 o;
        o.x = f2bf(xr.x - Tld[c0+i+0][q]);
        o.y = f2bf(xr.y - Tld[c0+i+1][q]);
        o.z = f2bf(xr.z - Tld[c0+i+2][q]);
        o.w = f2bf(xr.w - Tld[c0+i+3][q]);
        *(ushort4*)&attinb[row + c0 + i] = o;
      }
    }
  } else {
    // ---------- hm2 GEMM role: hm2b = bf16(x@(Wn@Wm2) + fb2) ----------
    u16* Wsw = (u16*)smem;   // 128 rows x 256 B = 32768 B
    const int w4 = t >> 6;
    const int lane = t & 63;
    const int l31 = lane & 31;
    const int hi = lane >> 5;
    const int rb = ((int)blockIdx.x - nstrips) * 32;
    #pragma unroll
    for (int i=0;i<8;i++){
      int slot = i*256 + t;
      int row = slot >> 4, g = slot & 15;
      short8 v = *(const short8*)(W1T + row*128 + g*8);
      *(short8*)((char*)Wsw + row*256 + ((g ^ (row&7))*16)) = v;
    }
    short8 af[8];
    #pragma unroll
    for (int g=0; g<8; g++)
      af[g] = *(const short8*)(xb + (size_t)(rb + l31)*D + (2*g + hi)*8);
    __syncthreads();
    f32x16 acc1;
    #pragma unroll
    for (int i=0;i<16;i++) acc1[i]=0.f;
    const int wrow = w4*32 + l31;
    #pragma unroll
    for (int s=0;s<8;s++){
      int gr = 2*s + hi;
      short8 wf = *(const short8*)((const char*)Wsw + wrow*256 + ((gr ^ (wrow&7))*16));
      acc1 = __builtin_amdgcn_mfma_f32_32x32x16_bf16(af[s], wf, acc1, 0,0,0);
    }
    float bv = fb2[wrow];
    #pragma unroll
    for (int r=0;r<16;r++){
      int rr = (r&3) + 8*(r>>2) + 4*hi;
      hm2b[(size_t)(rb + rr)*D + wrow] = f2bf(acc1[r] + bv);
    }
  }
}

// ---------------- norm + f32/bf16/bf16T write fused ----------------
__global__ __launch_bounds__(256) void k_normcvt(const float* __restrict__ outb,
                        const float* __restrict__ sums,
                        const float* __restrict__ gamma, const float* __restrict__ beta,
                        int N, float* __restrict__ x, u16* __restrict__ xb, u16* __restrict__ xbT){
  __shared__ u16 tile[128][136];
  __shared__ float smu[128], srs[128], sg2[128], sb2[128];
  int t = threadIdx.x;
  if (t < 128){
    float mu = sums[t] / (float)N;
    float var = fmaxf(sums[128+t]/(float)N - mu*mu, 0.0f);
    smu[t]=mu; srs[t]=rsqrtf(var + 1e-5f);
    sg2[t]=gamma[t]; sb2[t]=beta[t];
  }
  __syncthreads();
  int nb = blockIdx.x * 128;
  int n = t >> 1, ch = t & 1;
  #pragma unroll
  for (int i=0;i<16;i++){
    int dd = ch*64 + i*4;
    float4 v = *(const float4*)&outb[(size_t)(nb+n)*D + dd];
    float4 y;
    y.x = (v.x - smu[dd+0])*srs[dd+0]*sg2[dd+0] + sb2[dd+0];
    y.y = (v.y - smu[dd+1])*srs[dd+1]*sg2[dd+1] + sb2[dd+1];
    y.z = (v.z - smu[dd+2])*srs[dd+2]*sg2[dd+2] + sb2[dd+2];
    y.w = (v.w - smu[dd+3])*srs[dd+3]*sg2[dd+3] + sb2[dd+3];
    *(float4*)&x[(size_t)(nb+n)*D + dd] = y;
    u16 b0=f2bf(y.x), b1=f2bf(y.y), b2=f2bf(y.z), b3=f2bf(y.w);
    ushort4 uv; uv.x=b0; uv.y=b1; uv.z=b2; uv.w=b3;
    *(ushort4*)&xb[(size_t)(nb+n)*D + dd] = uv;
    tile[dd+0][n]=b0; tile[dd+1][n]=b1; tile[dd+2][n]=b2; tile[dd+3][n]=b3;
  }
  __syncthreads();
  int d = t & 127, hf = t >> 7;
  #pragma unroll
  for (int i=0;i<8;i++){
    short8 v = *(const short8*)&tile[d][hf*64 + i*8];
    *(short8*)&xbT[(size_t)d*N + nb + hf*64 + i*8] = v;
  }
}

// ---------------- gated readout ----------------
__global__ __launch_bounds__(256) void k_gatepool(
    const float* __restrict__ states, const float* __restrict__ glog,
    int N1, int N, float* __restrict__ gsums)
{
  __shared__ float part[256];
  part[threadIdx.x] = 0.f;
  __syncthreads();
  int wid = threadIdx.x >> 6, lane = threadIdx.x & 63;
  for (int v = blockIdx.x*4 + wid; v < N; v += gridDim.x*4){
    float a0 = glog[(size_t)v*D + lane], a1 = glog[(size_t)v*D + lane + 64];
    float mx = fmaxf(a0,a1);
    #pragma unroll
    for (int off=32; off; off>>=1) mx = fmaxf(mx, __shfl_xor(mx, off, 64));
    float e0 = __expf(a0-mx), e1 = __expf(a1-mx);
    float ss = e0+e1;
    #pragma unroll
    for (int off=32; off; off>>=1) ss += __shfl_xor(ss, off, 64);
    float inv = 1.f/ss;
    int g = (v < N1) ? 0 : 1;
    atomicAdd(&part[g*128 + lane], states[(size_t)v*D+lane]*e0*inv);
    atomicAdd(&part[g*128 + lane + 64], states[(size_t)v*D+lane+64]*e1*inv);
  }
  __syncthreads();
  atomicAdd(&gsums[threadIdx.x], part[threadIdx.x]);
}

__global__ __launch_bounds__(256) void k_emb(
    const float* __restrict__ gsums, const float* __restrict__ Wf,
    const float* __restrict__ bf_, int N1, int N2, float* __restrict__ outp)
{
  __shared__ float mean[256];
  int t = threadIdx.x;
  mean[t] = gsums[t] / ((t < 128) ? (float)N1 : (float)N2);
  __syncthreads();
  int g = t >> 7, dc = t & 127;
  float acc = bf_[dc];
  for (int k=0;k<D;k++) acc += mean[g*128 + k] * Wf[k*D + dc];
  outp[t] = acc;
}

extern "C" void kernel_launch(void* const* d_in, const int* in_sizes, int n_in,
                              void* d_out, int out_size, void* d_ws, size_t ws_size,
                              hipStream_t stream) {
  const float* feats1 = (const float*)d_in[0];
  const int*   ei1    = (const int*)d_in[1];
  const float* feats2 = (const float*)d_in[2];
  const int*   ei2    = (const int*)d_in[3];
  const float* Wn = (const float*)d_in[6];
  const float* bn = (const float*)d_in[7];
  const float* Wm = (const float*)d_in[8];
  const float* bm = (const float*)d_in[9];
  const float* Wp = (const float*)d_in[10];
  const float* bp = (const float*)d_in[11];
  const float* gamma = (const float*)d_in[12];
  const float* beta  = (const float*)d_in[13];
  const float* Wa = (const float*)d_in[14];
  const float* ba = (const float*)d_in[15];
  const float* Wg = (const float*)d_in[16];
  const float* bg = (const float*)d_in[17];
  const float* Wf = (const float*)d_in[18];
  const float* bff = (const float*)d_in[19];

  int N1 = in_sizes[0]/D, E1 = in_sizes[1]/2;
  int N2 = in_sizes[2]/D, E2 = in_sizes[3]/2;
  int N = N1+N2;
  int nstrips = N/32;

  char* w = (char*)d_ws;
  float* x    = (float*)w; w += (size_t)N*D*4;
  u16* xb     = (u16*)w;   w += (size_t)N*D*2;
  u16* xbT    = (u16*)w;   w += (size_t)N*D*2;
  u16* hm2b   = (u16*)w;   w += (size_t)N*D*2;
  u16* aggrb  = (u16*)w;   w += (size_t)N*D*2;
  u16* attinb = (u16*)w;   w += (size_t)N*D*2;
  // contiguous zero-init region: cnt | sums(3x256) | gsums(256)
  int* cnt    = (int*)w;   w += (size_t)N*4;
  float* sums = (float*)w; w += 3*256*4;
  float* gsums= (float*)w; w += 256*4;
  int* ptr    = (int*)w;   w += (size_t)N*4;
  int* cursor = (int*)w;   w += (size_t)N*4;
  float* degf = (float*)w; w += (size_t)N*4;
  int* srclist= (int*)w;   w += (size_t)(E1+E2)*4;
  u16* wgt    = (u16*)w;   w += (size_t)8*16384*2;
  u16* wfu    = (u16*)w;   w += (size_t)6*16384*2;
  float* fbias= (float*)w; w += (size_t)6*128*4;
  u16* Opartb = (u16*)w;   w += (size_t)nstrips*KVS*4096*2;
  float* MLpart=(float*)w; w += (size_t)nstrips*KVS*64*4;
  // lifetime-disjoint f32 aliases inside Opartb:
  float* Sg     = (float*)Opartb;
  float* outb   = (float*)Opartb + (size_t)N*D;
  float* states = Sg;
  float* glog   = outb;

  hipMemsetAsync(cnt, 0, (size_t)N*4 + 4*256*4, stream);
  k_count<<<1024,256,0,stream>>>(ei1, ei2, E1, E2, N1, cnt);
  k_scan<<<1,256,0,stream>>>(cnt, ptr, cursor, degf, N);
  k_fill<<<1024,256,0,stream>>>(ei1, ei2, E1, E2, N1, cursor, srclist);
  k_prep<<<14 + N/128,256,0,stream>>>(Wp, Wa, Wg, Wn, Wm, bn, bm,
                                      feats1, feats2, N1, wgt, wfu, fbias, x, xb, xbT, N);

  for (int l=0;l<3;l++){
    const u16* fuse2T_l = wfu + (size_t)l*16384;
    const u16* fuse1T_l = wfu + (size_t)(3+l)*16384;
    const float* fb2_l  = fbias + (size_t)l*128;
    const float* fb1_l  = fbias + (size_t)(3+l)*128;
    const u16* Wp1T_l = wgt + (size_t)(0+l)*16384;
    const u16* Wp2T_l = wgt + (size_t)(3+l)*16384;
    const float* bp_l = bp + (size_t)l*D;
    float* sums_l = sums + (size_t)l*256;

    k_flash_mfma<<<(N/128)*KVS,256,0,stream>>>(xb, xbT, N1, N2, N, Opartb, MLpart);
    // fused: fcomb (attinb) + hm2 GEMM
    k_fcomb_hm2<<<nstrips + N/32,256,0,stream>>>(Opartb, MLpart, x, attinb,
                                                 xb, fuse2T_l, fb2_l, hm2b, nstrips, N);
    k_gather<<<N/2,256,0,stream>>>(hm2b, ptr, cnt, srclist, Sg, N);
    // aggr = deg.*(x@(Wn@Wm1) + fb1) + Sg
    k_gemm<<<N/32,256,0,stream>>>(xb, fuse1T_l, nullptr, nullptr, fb1_l, nullptr,
                                  degf, Sg, nullptr, nullptr, aggrb, nullptr, N);
    // outb = aggr@Wp_top + attin@Wp_bot + bp (f32 out, fused column sums)
    k_gemm<<<N/32,256,0,stream>>>(aggrb, Wp1T_l, attinb, Wp2T_l, bp_l, nullptr,
                                  nullptr, nullptr, outb, nullptr, nullptr, sums_l, N);
    k_normcvt<<<N/128,256,0,stream>>>(outb, sums_l, gamma + (size_t)l*D, beta + (size_t)l*D, N, x, xb, xbT);
  }

  // readout: states = x@Wa+ba, glog = x@Wg+bg in one dual-output GEMM
  k_gemm<<<N/32,256,0,stream>>>(xb, wgt + (size_t)6*16384, xb, wgt + (size_t)7*16384,
                                ba, bg, nullptr, nullptr, states, glog, nullptr, nullptr, N);
  k_gatepool<<<64,256,0,stream>>>(states, glog, N1, N, gsums);
  k_emb<<<1,256,0,stream>>>(gsums, Wf, bff, N1, N2, (float*)d_out);
}

// Round 13
// 603.962 us; speedup vs baseline: 1.3291x; 1.0507x over previous
//
#include <hip/hip_runtime.h>
#include <hip/hip_bf16.h>

#define D 128
#define KVS 16
typedef unsigned short u16;
typedef unsigned int u32;
typedef __attribute__((ext_vector_type(8))) short short8;
typedef __attribute__((ext_vector_type(16))) float f32x16;
typedef __attribute__((ext_vector_type(4))) u32 u32x4;

__device__ __forceinline__ u16 f2bf(float f){
  u32 u = __builtin_bit_cast(u32, f);
  u32 r = (u + 0x7FFFu + ((u >> 16) & 1u)) >> 16;
  return (u16)r;
}
__device__ __forceinline__ float bf2f(u16 u){
  union { u32 i; float f; } v; v.i = ((u32)u) << 16; return v.f;
}

// ---------------- CSR build ----------------
__global__ void k_count(const int* __restrict__ ei1, const int* __restrict__ ei2,
                        int E1, int E2, int N1, int* __restrict__ cnt){
  int i = blockIdx.x*blockDim.x + threadIdx.x;
  int Et = E1 + E2;
  for (; i < Et; i += gridDim.x*blockDim.x){
    int dst = (i < E1) ? ei1[E1 + i] : (ei2[E2 + (i - E1)] + N1);
    atomicAdd(&cnt[dst], 1);
  }
}

__global__ void k_scan(const int* __restrict__ cnt, int* __restrict__ ptr,
                       int* __restrict__ cursor, float* __restrict__ degf, int N){
  __shared__ int part[256];
  int t = threadIdx.x;
  int per = (N + 255) >> 8;
  int lo = t*per, hi = min(N, lo+per);
  int s = 0;
  for (int j=lo;j<hi;j++) s += cnt[j];
  part[t] = s; __syncthreads();
  if (t==0){ int acc=0; for (int j=0;j<256;j++){ int v=part[j]; part[j]=acc; acc+=v; } }
  __syncthreads();
  int acc = part[t];
  for (int j=lo;j<hi;j++){ ptr[j]=acc; cursor[j]=acc; degf[j]=(float)cnt[j]; acc += cnt[j]; }
}

__global__ void k_fill(const int* __restrict__ ei1, const int* __restrict__ ei2,
                       int E1, int E2, int N1, int* __restrict__ cursor, int* __restrict__ srclist){
  int i = blockIdx.x*blockDim.x + threadIdx.x;
  int Et = E1 + E2;
  for (; i < Et; i += gridDim.x*blockDim.x){
    int src, dst;
    if (i < E1){ src = ei1[i]; dst = ei1[E1+i]; }
    else { int j = i - E1; src = ei2[j] + N1; dst = ei2[E2+j] + N1; }
    int p = atomicAdd(&cursor[dst], 1);
    srclist[p] = src;
  }
}

// ---------------- merged prologue: wcvt (blocks 0..7) | wfuse (8..13) | cvt0 (14..) ----------------
__global__ __launch_bounds__(256) void k_prep(
    const float* __restrict__ Wp, const float* __restrict__ Wa, const float* __restrict__ Wg,
    const float* __restrict__ Wn, const float* __restrict__ Wm,
    const float* __restrict__ bn, const float* __restrict__ bm,
    const float* __restrict__ src1, const float* __restrict__ src2, int N1,
    u16* __restrict__ wgt, u16* __restrict__ wfu, float* __restrict__ fbias,
    float* __restrict__ x, u16* __restrict__ xb, u16* __restrict__ xbT, int N)
{
  __shared__ u16 tile[128][136];
  const int m = blockIdx.x;
  const int t = threadIdx.x;
  if (m < 8){
    // ---- wcvt: f32 [128k][128n] -> bf16 transposed [128n][128k]
    const float* src; u16* dst;
    if (m < 6){ int l = m % 3, half = m / 3; src = Wp + (size_t)l*32768 + half*16384; dst = wgt + (size_t)(half*3 + l)*16384; }
    else if (m == 6){ src = Wa; dst = wgt + (size_t)6*16384; }
    else { src = Wg; dst = wgt + (size_t)7*16384; }
    int n = t & 127, rh = t >> 7;
    for (int r0=0; r0<128; r0+=2){
      int r = r0 + rh;
      tile[n][r] = f2bf(src[r*128 + n]);
    }
    __syncthreads();
    int row = t >> 1, ch = t & 1;
    #pragma unroll
    for (int i=0;i<4;i++){
      int k0 = ch*64 + i*16;
      short8 a = *(const short8*)&tile[row][k0];
      short8 b = *(const short8*)&tile[row][k0+8];
      *(short8*)&dst[row*128 + k0] = a;
      *(short8*)&dst[row*128 + k0 + 8] = b;
    }
  } else if (m < 14){
    // ---- wfuse (fast): wfu[l]=(Wn_l@Wm2_l)^T, wfu[3+l]=(Wn_l@Wm1_l)^T; bias' for aggr GEMM
    int blk = m - 8;
    int l = blk % 3, which = blk / 3;  // which 0: Wm2 (bottom half), 1: Wm1 (top half)
    const float* A  = Wn + (size_t)l*16384;
    const float* Bm = Wm + (size_t)l*32768 + (which==0 ? 16384 : 0);
    u16* dst  = wfu  + (size_t)(which==0 ? l : 3+l)*16384;
    // stage A transposed as bf16: tile[k][r] = bf16(A[r][k])
    {
      int r = t >> 1, kh = t & 1;
      #pragma unroll
      for (int i=0;i<16;i++){
        int k0 = kh*64 + i*4;
        float4 v4 = *(const float4*)&A[r*128 + k0];
        tile[k0+0][r] = f2bf(v4.x);
        tile[k0+1][r] = f2bf(v4.y);
        tile[k0+2][r] = f2bf(v4.z);
        tile[k0+3][r] = f2bf(v4.w);
      }
    }
    __syncthreads();
    int c0 = (t & 31) * 4;
    int r0 = (t >> 5) * 16;
    float acc[16][4];
    #pragma unroll
    for (int i=0;i<16;i++){ acc[i][0]=0.f; acc[i][1]=0.f; acc[i][2]=0.f; acc[i][3]=0.f; }
    for (int k=0;k<128;k++){
      float4 b4 = *(const float4*)&Bm[k*128 + c0];
      short8 a0 = *(const short8*)&tile[k][r0];
      short8 a1 = *(const short8*)&tile[k][r0+8];
      #pragma unroll
      for (int i=0;i<8;i++){
        float fa = bf2f((u16)a0[i]);
        acc[i][0] += fa*b4.x; acc[i][1] += fa*b4.y; acc[i][2] += fa*b4.z; acc[i][3] += fa*b4.w;
      }
      #pragma unroll
      for (int i=0;i<8;i++){
        float fa = bf2f((u16)a1[i]);
        acc[8+i][0] += fa*b4.x; acc[8+i][1] += fa*b4.y; acc[8+i][2] += fa*b4.z; acc[8+i][3] += fa*b4.w;
      }
    }
    #pragma unroll
    for (int i=0;i<16;i++)
      #pragma unroll
      for (int j=0;j<4;j++)
        dst[(size_t)(c0+j)*128 + (r0+i)] = f2bf(acc[i][j]);
    if (which == 1 && t < 128){
      // bias' = bn@(Wm1+Wm2) + bm  (deg-scaling distributes over both)
      const float* Bm1 = Wm + (size_t)l*32768;
      const float* Bm2 = Bm1 + 16384;
      float s = 0.f;
      for (int k=0;k<128;k++) s += bn[l*128+k]*(Bm1[k*128+t] + Bm2[k*128+t]);
      fbias[l*128+t] = s + bm[l*128+t];
    }
  } else {
    // ---- cvt0: feats -> x (f32), xb [N][128], xbT [128][N]
    int nb = (m - 14) * 128;
    int n = t >> 1, ch = t & 1;
    int row = nb + n;
    const float* srow = (row < N1) ? &src1[(size_t)row*D] : &src2[(size_t)(row-N1)*D];
    #pragma unroll
    for (int i=0;i<16;i++){
      int dd = ch*64 + i*4;
      float4 v = *(const float4*)&srow[dd];
      *(float4*)&x[(size_t)row*D + dd] = v;
      u16 b0 = f2bf(v.x), b1 = f2bf(v.y), b2 = f2bf(v.z), b3 = f2bf(v.w);
      ushort4 uv; uv.x=b0; uv.y=b1; uv.z=b2; uv.w=b3;
      *(ushort4*)&xb[(size_t)row*D + dd] = uv;
      tile[dd+0][n]=b0; tile[dd+1][n]=b1; tile[dd+2][n]=b2; tile[dd+3][n]=b3;
    }
    __syncthreads();
    int d = t & 127, hf = t >> 7;
    #pragma unroll
    for (int i=0;i<8;i++){
      short8 v = *(const short8*)&tile[d][hf*64 + i*8];
      *(short8*)&xbT[(size_t)d*N + nb + hf*64 + i*8] = v;
    }
  }
}

// ---------------- MFMA GEMM: v = rs.*(A@W1+bias) + addin + (of2? : B@W2); of/ob/of2 outputs ----------------
__global__ __launch_bounds__(256) void k_gemm(
    const u16* __restrict__ A, const u16* __restrict__ W1T,
    const u16* __restrict__ B, const u16* __restrict__ W2T,
    const float* __restrict__ bias, const float* __restrict__ bias2,
    const float* __restrict__ rs, const float* __restrict__ addin,
    float* __restrict__ of, float* __restrict__ of2,
    u16* __restrict__ ob, float* __restrict__ csums, int N)
{
  __shared__ __align__(16) u16 Wsw[2][16384];
  const int t = threadIdx.x;
  const int w4 = t >> 6;
  const int lane = t & 63;
  const int l31 = lane & 31;
  const int hi = lane >> 5;
  const int rb = blockIdx.x * 32;

  #pragma unroll
  for (int i=0;i<8;i++){
    int slot = i*256 + t;
    int row = slot >> 4, g = slot & 15;
    short8 v = *(const short8*)(W1T + row*128 + g*8);
    *(short8*)((char*)&Wsw[0][0] + row*256 + ((g ^ (row&7))*16)) = v;
  }
  if (B){
    #pragma unroll
    for (int i=0;i<8;i++){
      int slot = i*256 + t;
      int row = slot >> 4, g = slot & 15;
      short8 v = *(const short8*)(W2T + row*128 + g*8);
      *(short8*)((char*)&Wsw[1][0] + row*256 + ((g ^ (row&7))*16)) = v;
    }
  }
  short8 af[8], bfr[8];
  #pragma unroll
  for (int g=0; g<8; g++)
    af[g] = *(const short8*)(A + (size_t)(rb + l31)*D + (2*g + hi)*8);
  if (B){
    #pragma unroll
    for (int g=0; g<8; g++)
      bfr[g] = *(const short8*)(B + (size_t)(rb + l31)*D + (2*g + hi)*8);
  }
  __syncthreads();

  f32x16 acc1, acc2;
  #pragma unroll
  for (int i=0;i<16;i++){ acc1[i]=0.f; acc2[i]=0.f; }
  const int wrow = w4*32 + l31;   // output column
  #pragma unroll
  for (int s=0;s<8;s++){
    int gr = 2*s + hi;
    short8 wf = *(const short8*)((const char*)&Wsw[0][0] + wrow*256 + ((gr ^ (wrow&7))*16));
    acc1 = __builtin_amdgcn_mfma_f32_32x32x16_bf16(af[s], wf, acc1, 0,0,0);
  }
  if (B){
    #pragma unroll
    for (int s=0;s<8;s++){
      int gr = 2*s + hi;
      short8 wf = *(const short8*)((const char*)&Wsw[1][0] + wrow*256 + ((gr ^ (wrow&7))*16));
      acc2 = __builtin_amdgcn_mfma_f32_32x32x16_bf16(bfr[s], wf, acc2, 0,0,0);
    }
  }
  const int col = wrow;
  float bv = bias ? bias[col] : 0.0f;
  float bv2 = bias2 ? bias2[col] : 0.0f;
  float ssum = 0.f, sq = 0.f;
  #pragma unroll
  for (int r=0;r<16;r++){
    int rr = (r&3) + 8*(r>>2) + 4*hi;
    size_t grow = (size_t)(rb + rr);
    float v = acc1[r] + bv;
    if (rs) v *= rs[grow];
    if (addin) v += addin[grow*D + col];
    if (B && !of2) v += acc2[r];
    if (of) of[grow*D + col] = v;
    if (ob) ob[grow*D + col] = f2bf(v);
    if (of2) of2[grow*D + col] = acc2[r] + bv2;
    ssum += v; sq += v*v;
  }
  if (csums){
    ssum += __shfl_xor(ssum, 32, 64);
    sq   += __shfl_xor(sq, 32, 64);
    if (hi == 0){
      atomicAdd(&csums[col], ssum);
      atomicAdd(&csums[128+col], sq);
    }
  }
}

// xg[v] = sum over in-edges of xb[src] (bf16 in, bf16 out) — gather before GEMM (linearity)
__global__ __launch_bounds__(256) void k_gather(const u16* __restrict__ hb, const int* __restrict__ ptr,
                          const int* __restrict__ cnt, const int* __restrict__ srclist,
                          u16* __restrict__ xgb, int N){
  int f = threadIdx.x & 127, sub = threadIdx.x >> 7;
  int v = blockIdx.x*2 + sub;
  if (v >= N) return;
  int b = ptr[v], n = cnt[v];
  float a0=0.f, a1=0.f, a2=0.f, a3=0.f;
  int j=0;
  for (; j+3<n; j+=4){
    int s0=srclist[b+j], s1=srclist[b+j+1], s2=srclist[b+j+2], s3=srclist[b+j+3];
    a0 += bf2f(hb[(size_t)s0*D + f]);
    a1 += bf2f(hb[(size_t)s1*D + f]);
    a2 += bf2f(hb[(size_t)s2*D + f]);
    a3 += bf2f(hb[(size_t)s3*D + f]);
  }
  for (; j<n; j++) a0 += bf2f(hb[(size_t)srclist[b+j]*D + f]);
  xgb[(size_t)v*D + f] = f2bf((a0+a1)+(a2+a3));
}

// ---------------- MFMA flash cross-attention: exp2-domain defer-max, single acc chain, KVS=16 ----------------
__global__ __launch_bounds__(256, 2) void k_flash_mfma(
    const u16* __restrict__ xb, const u16* __restrict__ xbT,
    int N1, int N2, int Ntot,
    u16* __restrict__ Opartb, float* __restrict__ MLpart)
{
  __shared__ __align__(16) u16 Kbuf[2][4096];   // [32 key][128 d], granule^=(row&7)
  __shared__ __align__(16) u16 Vbuf[2][4096];   // [128 d][32 key], granule^=(d&3)

  const float L2E = 1.44269504f;
  const int t = threadIdx.x;
  const int w = t >> 6;
  const int lane = t & 63;
  const int l31 = lane & 31;
  const int hi = lane >> 5;

  const int qb = blockIdx.x / KVS;
  const int sp = blockIdx.x % KVS;
  const int qbase = qb * 128;
  const int qs = qbase + w*32;
  const bool isY = qbase >= N1;
  const int kv0 = isY ? 0 : N1;
  const int kvlen = isY ? N1 : N2;
  const int Lk = kvlen / KVS;
  const int kstart = kv0 + sp*Lk;
  const int ntiles = Lk >> 5;

  short8 qf[8];
  #pragma unroll
  for (int c = 0; c < 8; ++c)
    qf[c] = *(const short8*)(xb + (size_t)(qs + l31)*D + c*16 + hi*8);

  const int kr = t >> 3;
  const int kg = (t & 7) * 2;
  const int vd = t >> 1;
  const int vj = (t & 1) * 2;
  const int kw0 = kr*256 + ((kg     ^ (kr & 7))*16);
  const int kw1 = kr*256 + (((kg+1) ^ (kr & 7))*16);
  const int vw0 = vd*64  + (((vj     ^ vd) & 3)*16);
  const int vw1 = vd*64  + ((((vj+1) ^ vd) & 3)*16);

  f32x16 O[4];
  #pragma unroll
  for (int mt=0; mt<4; ++mt)
    #pragma unroll
    for (int i=0;i<16;i++) O[mt][i] = 0.f;
  float m_run = -3.0e38f, l_run = 0.0f;   // m_run in base-2 domain

  {
    int kb = kstart;
    short8 a0 = *(const short8*)(xb  + (size_t)(kb+kr)*D + kg*8);
    short8 a1 = *(const short8*)(xb  + (size_t)(kb+kr)*D + (kg+1)*8);
    short8 v0 = *(const short8*)(xbT + (size_t)vd*Ntot + kb + vj*8);
    short8 v1 = *(const short8*)(xbT + (size_t)vd*Ntot + kb + (vj+1)*8);
    *(short8*)((char*)&Kbuf[0][0] + kw0) = a0;
    *(short8*)((char*)&Kbuf[0][0] + kw1) = a1;
    *(short8*)((char*)&Vbuf[0][0] + vw0) = v0;
    *(short8*)((char*)&Vbuf[0][0] + vw1) = v1;
  }
  __syncthreads();

  for (int tt = 0; tt < ntiles; ++tt){
    const int cur = tt & 1;
    const int nxt = cur ^ 1;
    short8 a0, a1, v0, v1;
    const bool more = (tt+1 < ntiles);
    if (more){
      int kb = kstart + (tt+1)*32;
      a0 = *(const short8*)(xb  + (size_t)(kb+kr)*D + kg*8);
      a1 = *(const short8*)(xb  + (size_t)(kb+kr)*D + (kg+1)*8);
      v0 = *(const short8*)(xbT + (size_t)vd*Ntot + kb + vj*8);
      v1 = *(const short8*)(xbT + (size_t)vd*Ntot + kb + (vj+1)*8);
    }

    const char* Klds = (const char*)&Kbuf[cur][0];
    const char* Vlds = (const char*)&Vbuf[cur][0];

    // ---- S^T = K @ Q^T (single accumulator chain)
    f32x16 s;
    #pragma unroll
    for (int i=0;i<16;i++) s[i]=0.f;
    #pragma unroll
    for (int c = 0; c < 8; ++c){
      int gr = 2*c + hi;
      short8 ka = *(const short8*)(Klds + l31*256 + ((gr ^ (l31&7))*16));
      s = __builtin_amdgcn_mfma_f32_32x32x16_bf16(ka, qf[c], s, 0,0,0);
    }

    // ---- online softmax, base-2 domain, defer-max
    float tm = s[0];
    #pragma unroll
    for (int i=1;i<16;i++) tm = fmaxf(tm, s[i]);
    tm = fmaxf(tm, __shfl_xor(tm, 32, 64));
    float tm2 = tm * L2E;
    if (__any(tm2 > m_run + 11.544f)){
      float mnew = fmaxf(m_run, tm2);
      float alpha = exp2f(m_run - mnew);
      l_run *= alpha;
      m_run = mnew;
      #pragma unroll
      for (int i=0;i<16;i++){ O[0][i]*=alpha; O[1][i]*=alpha; O[2][i]*=alpha; O[3][i]*=alpha; }
    }
    float rsum = 0.f;
    #pragma unroll
    for (int i=0;i<16;i++){ float p = exp2f(fmaf(s[i], L2E, -m_run)); s[i]=p; rsum += p; }
    rsum += __shfl_xor(rsum, 32, 64);
    l_run += rsum;

    // ---- pack P to bf16 pairs
    u32 pk[8];
    #pragma unroll
    for (int i=0;i<8;i++){
      u32 r;
      asm("v_cvt_pk_bf16_f32 %0, %1, %2" : "=v"(r) : "v"(s[2*i]), "v"(s[2*i+1]));
      pk[i] = r;
    }

    // ---- PV: O^T += V^T @ P^T
    #pragma unroll
    for (int ks=0; ks<2; ++ks){
      u32 send0 = hi ? pk[(2*ks)*2+0] : pk[(2*ks+1)*2+0];
      u32 send1 = hi ? pk[(2*ks)*2+1] : pk[(2*ks+1)*2+1];
      u32 xv0 = (u32)__shfl_xor((int)send0, 32, 64);
      u32 xv1 = (u32)__shfl_xor((int)send1, 32, 64);
      u32 own0 = hi ? pk[(2*ks+1)*2+0] : pk[(2*ks)*2+0];
      u32 own1 = hi ? pk[(2*ks+1)*2+1] : pk[(2*ks)*2+1];
      u32x4 bv;
      bv.x = hi ? xv0 : own0;
      bv.y = hi ? xv1 : own1;
      bv.z = hi ? own0 : xv0;
      bv.w = hi ? own1 : xv1;
      short8 pf = __builtin_bit_cast(short8, bv);
      #pragma unroll
      for (int mt=0; mt<4; ++mt){
        int dd = mt*32 + l31;
        int j = 2*ks + hi;
        short8 vf = *(const short8*)(Vlds + dd*64 + (((j ^ dd) & 3)*16));
        O[mt] = __builtin_amdgcn_mfma_f32_32x32x16_bf16(vf, pf, O[mt], 0,0,0);
      }
    }

    if (more){
      *(short8*)((char*)&Kbuf[nxt][0] + kw0) = a0;
      *(short8*)((char*)&Kbuf[nxt][0] + kw1) = a1;
      *(short8*)((char*)&Vbuf[nxt][0] + vw0) = v0;
      *(short8*)((char*)&Vbuf[nxt][0] + vw1) = v1;
    }
    __syncthreads();
  }

  const int strip = qs >> 5;
  u16* Od = Opartb + ((size_t)strip*KVS + sp)*4096;
  #pragma unroll
  for (int mt=0; mt<4; ++mt){
    #pragma unroll
    for (int r=0;r<16;r++){
      int dd = mt*32 + (r&3) + 8*(r>>2) + 4*hi;
      Od[dd*32 + l31] = f2bf(O[mt][r]);
    }
  }
  if (lane < 32){
    float* mlp = MLpart + ((size_t)strip*KVS + sp)*64;
    mlp[l31*2+0] = m_run;
    mlp[l31*2+1] = l_run;
  }
}

// ---------------- flash partial combine: attinb = bf16(x - (sum_s w_s O_s)/L) ----------------
__global__ __launch_bounds__(256) void k_fcomb(
    const u16* __restrict__ Opartb, const float* __restrict__ MLpart,
    const float* __restrict__ x, u16* __restrict__ attinb)
{
  __shared__ float cw[KVS][32];
  __shared__ float Tld[128][33];
  const int strip = blockIdx.x;
  const int t = threadIdx.x;
  if (t < 32){
    const float* mlp = MLpart + (size_t)strip*KVS*64;
    float mv[KVS], lv[KVS];
    float M = -3.0e38f;
    #pragma unroll
    for (int s2=0;s2<KVS;s2++){ mv[s2]=mlp[s2*64+t*2]; lv[s2]=mlp[s2*64+t*2+1]; M = fmaxf(M, mv[s2]); }
    float L = 0.f;
    #pragma unroll
    for (int s2=0;s2<KVS;s2++){ float wv=exp2f(mv[s2]-M); cw[s2][t]=wv; L += wv*lv[s2]; }
    float inv = 1.0f / L;
    #pragma unroll
    for (int s2=0;s2<KVS;s2++) cw[s2][t] *= inv;
  }
  __syncthreads();
  {
    const int d = t >> 1, q0 = (t & 1) * 16;
    const u16* Ob = Opartb + (size_t)strip*KVS*4096;
    float acc[16];
    #pragma unroll
    for (int j=0;j<16;j++) acc[j]=0.f;
    #pragma unroll
    for (int s2=0; s2<KVS; ++s2){
      const u16* row = Ob + s2*4096 + d*32 + q0;
      short8 v8a = *(const short8*)row;
      short8 v8b = *(const short8*)(row + 8);
      #pragma unroll
      for (int j=0;j<8;j++){
        acc[j]   += cw[s2][q0+j]  *bf2f((u16)v8a[j]);
        acc[8+j] += cw[s2][q0+8+j]*bf2f((u16)v8b[j]);
      }
    }
    #pragma unroll
    for (int j=0;j<16;j++) Tld[d][q0+j] = acc[j];
  }
  __syncthreads();
  {
    const int q = t >> 3, c0 = (t & 7) * 16;
    const size_t row = (size_t)(strip*32 + q)*D;
    #pragma unroll
    for (int i=0;i<16;i+=4){
      float4 xr = *(const float4*)&x[row + c0 + i];
      ushort4 o;
      o.x = f2bf(xr.x - Tld[c0+i+0][q]);
      o.y = f2bf(xr.y - Tld[c0+i+1][q]);
      o.z = f2bf(xr.z - Tld[c0+i+2][q]);
      o.w = f2bf(xr.w - Tld[c0+i+3][q]);
      *(ushort4*)&attinb[row + c0 + i] = o;
    }
  }
}

// ---------------- norm + f32/bf16/bf16T write fused ----------------
__global__ __launch_bounds__(256) void k_normcvt(const float* __restrict__ outb,
                        const float* __restrict__ sums,
                        const float* __restrict__ gamma, const float* __restrict__ beta,
                        int N, float* __restrict__ x, u16* __restrict__ xb, u16* __restrict__ xbT){
  __shared__ u16 tile[128][136];
  __shared__ float smu[128], srs[128], sg2[128], sb2[128];
  int t = threadIdx.x;
  if (t < 128){
    float mu = sums[t] / (float)N;
    float var = fmaxf(sums[128+t]/(float)N - mu*mu, 0.0f);
    smu[t]=mu; srs[t]=rsqrtf(var + 1e-5f);
    sg2[t]=gamma[t]; sb2[t]=beta[t];
  }
  __syncthreads();
  int nb = blockIdx.x * 128;
  int n = t >> 1, ch = t & 1;
  #pragma unroll
  for (int i=0;i<16;i++){
    int dd = ch*64 + i*4;
    float4 v = *(const float4*)&outb[(size_t)(nb+n)*D + dd];
    float4 y;
    y.x = (v.x - smu[dd+0])*srs[dd+0]*sg2[dd+0] + sb2[dd+0];
    y.y = (v.y - smu[dd+1])*srs[dd+1]*sg2[dd+1] + sb2[dd+1];
    y.z = (v.z - smu[dd+2])*srs[dd+2]*sg2[dd+2] + sb2[dd+2];
    y.w = (v.w - smu[dd+3])*srs[dd+3]*sg2[dd+3] + sb2[dd+3];
    *(float4*)&x[(size_t)(nb+n)*D + dd] = y;
    u16 b0=f2bf(y.x), b1=f2bf(y.y), b2=f2bf(y.z), b3=f2bf(y.w);
    ushort4 uv; uv.x=b0; uv.y=b1; uv.z=b2; uv.w=b3;
    *(ushort4*)&xb[(size_t)(nb+n)*D + dd] = uv;
    tile[dd+0][n]=b0; tile[dd+1][n]=b1; tile[dd+2][n]=b2; tile[dd+3][n]=b3;
  }
  __syncthreads();
  int d = t & 127, hf = t >> 7;
  #pragma unroll
  for (int i=0;i<8;i++){
    short8 v = *(const short8*)&tile[d][hf*64 + i*8];
    *(short8*)&xbT[(size_t)d*N + nb + hf*64 + i*8] = v;
  }
}

// ---------------- gated readout ----------------
__global__ __launch_bounds__(256) void k_gatepool(
    const float* __restrict__ states, const float* __restrict__ glog,
    int N1, int N, float* __restrict__ gsums)
{
  __shared__ float part[256];
  part[threadIdx.x] = 0.f;
  __syncthreads();
  int wid = threadIdx.x >> 6, lane = threadIdx.x & 63;
  for (int v = blockIdx.x*4 + wid; v < N; v += gridDim.x*4){
    float a0 = glog[(size_t)v*D + lane], a1 = glog[(size_t)v*D + lane + 64];
    float mx = fmaxf(a0,a1);
    #pragma unroll
    for (int off=32; off; off>>=1) mx = fmaxf(mx, __shfl_xor(mx, off, 64));
    float e0 = __expf(a0-mx), e1 = __expf(a1-mx);
    float ss = e0+e1;
    #pragma unroll
    for (int off=32; off; off>>=1) ss += __shfl_xor(ss, off, 64);
    float inv = 1.f/ss;
    int g = (v < N1) ? 0 : 1;
    atomicAdd(&part[g*128 + lane], states[(size_t)v*D+lane]*e0*inv);
    atomicAdd(&part[g*128 + lane + 64], states[(size_t)v*D+lane+64]*e1*inv);
  }
  __syncthreads();
  atomicAdd(&gsums[threadIdx.x], part[threadIdx.x]);
}

__global__ __launch_bounds__(256) void k_emb(
    const float* __restrict__ gsums, const float* __restrict__ Wf,
    const float* __restrict__ bf_, int N1, int N2, float* __restrict__ outp)
{
  __shared__ float mean[256];
  int t = threadIdx.x;
  mean[t] = gsums[t] / ((t < 128) ? (float)N1 : (float)N2);
  __syncthreads();
  int g = t >> 7, dc = t & 127;
  float acc = bf_[dc];
  for (int k=0;k<D;k++) acc += mean[g*128 + k] * Wf[k*D + dc];
  outp[t] = acc;
}

extern "C" void kernel_launch(void* const* d_in, const int* in_sizes, int n_in,
                              void* d_out, int out_size, void* d_ws, size_t ws_size,
                              hipStream_t stream) {
  const float* feats1 = (const float*)d_in[0];
  const int*   ei1    = (const int*)d_in[1];
  const float* feats2 = (const float*)d_in[2];
  const int*   ei2    = (const int*)d_in[3];
  const float* Wn = (const float*)d_in[6];
  const float* bn = (const float*)d_in[7];
  const float* Wm = (const float*)d_in[8];
  const float* bm = (const float*)d_in[9];
  const float* Wp = (const float*)d_in[10];
  const float* bp = (const float*)d_in[11];
  const float* gamma = (const float*)d_in[12];
  const float* beta  = (const float*)d_in[13];
  const float* Wa = (const float*)d_in[14];
  const float* ba = (const float*)d_in[15];
  const float* Wg = (const float*)d_in[16];
  const float* bg = (const float*)d_in[17];
  const float* Wf = (const float*)d_in[18];
  const float* bff = (const float*)d_in[19];

  int N1 = in_sizes[0]/D, E1 = in_sizes[1]/2;
  int N2 = in_sizes[2]/D, E2 = in_sizes[3]/2;
  int N = N1+N2;
  int nstrips = N/32;

  char* w = (char*)d_ws;
  float* x    = (float*)w; w += (size_t)N*D*4;
  u16* xb     = (u16*)w;   w += (size_t)N*D*2;
  u16* xbT    = (u16*)w;   w += (size_t)N*D*2;
  u16* xgb    = (u16*)w;   w += (size_t)N*D*2;
  u16* aggrb  = (u16*)w;   w += (size_t)N*D*2;
  u16* attinb = (u16*)w;   w += (size_t)N*D*2;
  // contiguous zero-init region: cnt | sums(3x256) | gsums(256)
  int* cnt    = (int*)w;   w += (size_t)N*4;
  float* sums = (float*)w; w += 3*256*4;
  float* gsums= (float*)w; w += 256*4;
  int* ptr    = (int*)w;   w += (size_t)N*4;
  int* cursor = (int*)w;   w += (size_t)N*4;
  float* degf = (float*)w; w += (size_t)N*4;
  int* srclist= (int*)w;   w += (size_t)(E1+E2)*4;
  u16* wgt    = (u16*)w;   w += (size_t)8*16384*2;
  u16* wfu    = (u16*)w;   w += (size_t)6*16384*2;
  float* fbias= (float*)w; w += (size_t)3*128*4;
  u16* Opartb = (u16*)w;   w += (size_t)nstrips*KVS*4096*2;
  float* MLpart=(float*)w; w += (size_t)nstrips*KVS*64*4;
  // lifetime-disjoint f32 aliases inside Opartb:
  float* outb   = (float*)Opartb + (size_t)N*D;
  float* states = (float*)Opartb;
  float* glog   = outb;

  hipMemsetAsync(cnt, 0, (size_t)N*4 + 4*256*4, stream);
  k_count<<<1024,256,0,stream>>>(ei1, ei2, E1, E2, N1, cnt);
  k_scan<<<1,256,0,stream>>>(cnt, ptr, cursor, degf, N);
  k_fill<<<1024,256,0,stream>>>(ei1, ei2, E1, E2, N1, cursor, srclist);
  k_prep<<<14 + N/128,256,0,stream>>>(Wp, Wa, Wg, Wn, Wm, bn, bm,
                                      feats1, feats2, N1, wgt, wfu, fbias, x, xb, xbT, N);

  for (int l=0;l<3;l++){
    const u16* fuse2T_l = wfu + (size_t)l*16384;
    const u16* fuse1T_l = wfu + (size_t)(3+l)*16384;
    const float* fb_l   = fbias + (size_t)l*128;
    const u16* Wp1T_l = wgt + (size_t)(0+l)*16384;
    const u16* Wp2T_l = wgt + (size_t)(3+l)*16384;
    const float* bp_l = bp + (size_t)l*D;
    float* sums_l = sums + (size_t)l*256;

    k_flash_mfma<<<(N/128)*KVS,256,0,stream>>>(xb, xbT, N1, N2, N, Opartb, MLpart);
    k_fcomb<<<nstrips,256,0,stream>>>(Opartb, MLpart, x, attinb);
    // xg = sum of neighbor xb rows (linearity: gather before GEMM)
    k_gather<<<N/2,256,0,stream>>>(xb, ptr, cnt, srclist, xgb, N);
    // aggr = deg.*(xb@fuse1 + bias') + xg@fuse2
    k_gemm<<<N/32,256,0,stream>>>(xb, fuse1T_l, xgb, fuse2T_l, fb_l, nullptr,
                                  degf, nullptr, nullptr, nullptr, aggrb, nullptr, N);
    // outb = aggr@Wp_top + attin@Wp_bot + bp (f32 out, fused column sums)
    k_gemm<<<N/32,256,0,stream>>>(aggrb, Wp1T_l, attinb, Wp2T_l, bp_l, nullptr,
                                  nullptr, nullptr, outb, nullptr, nullptr, sums_l, N);
    k_normcvt<<<N/128,256,0,stream>>>(outb, sums_l, gamma + (size_t)l*D, beta + (size_t)l*D, N, x, xb, xbT);
  }

  // readout: states = x@Wa+ba, glog = x@Wg+bg in one dual-output GEMM
  k_gemm<<<N/32,256,0,stream>>>(xb, wgt + (size_t)6*16384, xb, wgt + (size_t)7*16384,
                                ba, bg, nullptr, nullptr, states, glog, nullptr, nullptr, N);
  k_gatepool<<<64,256,0,stream>>>(states, glog, N1, N, gsums);
  k_emb<<<1,256,0,stream>>>(gsums, Wf, bff, N1, N2, (float*)d_out);
}